// Round 1
// baseline (1887.499 us; speedup 1.0000x reference)
//
#include <hip/hip_runtime.h>

#define cN 16384
#define cE 65536
#define cT 2048

typedef __attribute__((ext_vector_type(8))) short short8;
typedef __attribute__((ext_vector_type(4))) float f32x4;

__device__ __forceinline__ short f2bf(float f){
  unsigned u = __float_as_uint(f);
  u = (u + 0x7FFFu + ((u >> 16) & 1u)) >> 16;
  return (short)u;
}
__device__ __forceinline__ float bf2f(short s){
  return __uint_as_float(((unsigned)(unsigned short)s) << 16);
}
__device__ __forceinline__ float sigm(float x){ return 1.f / (1.f + __expf(-x)); }
__device__ __forceinline__ unsigned fenc(float f){
  unsigned u = __float_as_uint(f);
  return (u & 0x80000000u) ? ~u : (u | 0x80000000u);
}
__device__ __forceinline__ float fdec(unsigned u){
  u = (u & 0x80000000u) ? (u & 0x7FFFFFFFu) : ~u;
  return __uint_as_float(u);
}

// out = relu(x @ W_lin0.T + b)
__global__ __launch_bounds__(256) void k_lin0(const float* __restrict__ x,
    const float* __restrict__ W, const float* __restrict__ b, float* __restrict__ out)
{
  int i = blockIdx.x * 256 + threadIdx.x;       // cN*64
  int n = i >> 6, f = i & 63;
  float acc = b[f] + x[n*3]*W[f*3] + x[n*3+1]*W[f*3+1] + x[n*3+2]*W[f*3+2];
  out[i] = fmaxf(acc, 0.f);
}

// h1 = bf16(relu(edge_attr @ W_e1.T + b_e1))
__global__ __launch_bounds__(256) void k_h1(const float* __restrict__ ea,
    const float* __restrict__ W, const float* __restrict__ b, short* __restrict__ h1)
{
  int i = blockIdx.x * 256 + threadIdx.x;       // cE*128
  int e = i >> 7, k = i & 127;
  const float* a = ea + e * 7;
  const float* w = W + k * 7;
  float acc = b[k];
  #pragma unroll
  for (int c = 0; c < 7; c++) acc += a[c] * w[c];
  h1[i] = f2bf(fmaxf(acc, 0.f));
}

// permute W_e2 rows j=d*64+f -> j'=f*64+d, convert bf16; permute bias too
__global__ __launch_bounds__(256) void k_w2perm(const float* __restrict__ W2,
    const float* __restrict__ b2, short* __restrict__ w2p, float* __restrict__ b2p)
{
  int i = blockIdx.x * 256 + threadIdx.x;       // 4096*128
  int jp = i >> 7, k = i & 127;
  int f = jp >> 6, d = jp & 63;
  int j = d * 64 + f;
  w2p[i] = f2bf(W2[j * 128 + k]);
  if (k == 0) b2p[jp] = b2[j];
}

__global__ __launch_bounds__(256) void k_cnt(const int* __restrict__ ei, float* __restrict__ cnt)
{
  int e = blockIdx.x * 256 + threadIdx.x;
  if (e < cE) atomicAdd(&cnt[ei[cE + e]], 1.0f);
}

// ew'[row][f*64+d] = h1[row] . w2p[f*64+d] + b2p  (bf16 out). Block: 64 rows x 256 cols.
__global__ __launch_bounds__(256) void k_gemm(const short* __restrict__ h1,
    const short* __restrict__ w2p, const float* __restrict__ b2p,
    short* __restrict__ ew, int e0)
{
  int wid = threadIdx.x >> 6, lane = threadIdx.x & 63;
  int r16 = lane & 15, kg = lane >> 4;
  int rowbase = blockIdx.x * 64;                 // chunk-local row
  int colbase = blockIdx.y * 256 + wid * 64;
  const short* Ab = h1 + (size_t)(e0 + rowbase + r16) * 128 + kg * 8;
  const short* Bb = w2p + (size_t)(colbase + r16) * 128 + kg * 8;
  f32x4 acc[4][4] = {};
  #pragma unroll
  for (int kk = 0; kk < 4; kk++){
    short8 af[4], bfr[4];
    #pragma unroll
    for (int i = 0; i < 4; i++) af[i] = *(const short8*)(Ab + i*16*128 + kk*32);
    #pragma unroll
    for (int j = 0; j < 4; j++) bfr[j] = *(const short8*)(Bb + j*16*128 + kk*32);
    #pragma unroll
    for (int i = 0; i < 4; i++)
      #pragma unroll
      for (int j = 0; j < 4; j++)
        acc[i][j] = __builtin_amdgcn_mfma_f32_16x16x32_bf16(af[i], bfr[j], acc[i][j], 0, 0, 0);
  }
  #pragma unroll
  for (int i = 0; i < 4; i++){
    int rl = rowbase + i * 16 + kg * 4;
    #pragma unroll
    for (int j = 0; j < 4; j++){
      int col = colbase + j * 16 + r16;
      float bias = b2p[col];
      size_t base = (size_t)rl * 4096 + col;
      #pragma unroll
      for (int q = 0; q < 4; q++)
        ew[base + (size_t)q * 4096] = f2bf(acc[i][j][q] + bias);
    }
  }
}

// msg[e,f] = sum_d out[src,d]*ew'[e][f*64+d];  atomicAdd into aggr[tgt]
__global__ __launch_bounds__(256) void k_msg(const short* __restrict__ ew,
    const float* __restrict__ out, const int* __restrict__ ei,
    float* __restrict__ aggr, int e0)
{
  __shared__ float so[4][64];
  int wid = threadIdx.x >> 6, lane = threadIdx.x & 63;
  int el = blockIdx.x * 4 + wid;
  int e = e0 + el;
  int s = ei[e], t = ei[cE + e];
  so[wid][lane] = out[s * 64 + lane];
  __syncthreads();
  const short* row = ew + (size_t)el * 4096 + lane * 64;
  float acc = 0.f;
  #pragma unroll
  for (int c = 0; c < 8; c++){
    short8 v = *(const short8*)(row + c * 8);
    f32x4 o0 = *(const f32x4*)(&so[wid][c * 8]);
    f32x4 o1 = *(const f32x4*)(&so[wid][c * 8 + 4]);
    acc += bf2f(v[0]) * o0[0]; acc += bf2f(v[1]) * o0[1];
    acc += bf2f(v[2]) * o0[2]; acc += bf2f(v[3]) * o0[3];
    acc += bf2f(v[4]) * o1[0]; acc += bf2f(v[5]) * o1[1];
    acc += bf2f(v[6]) * o1[2]; acc += bf2f(v[7]) * o1[3];
  }
  atomicAdd(&aggr[t * 64 + lane], acc);
}

// node update: m = relu(aggr/cnt + out@conv + cb); GRU(m, out) -> out (in place)
__global__ __launch_bounds__(512) void k_node(float* __restrict__ out,
    const float* __restrict__ aggr, const float* __restrict__ cnt,
    const float* __restrict__ convW, const float* __restrict__ convB,
    const float* __restrict__ Wih, const float* __restrict__ Whh,
    const float* __restrict__ bih, const float* __restrict__ bhh)
{
  __shared__ float sconv[64 * 64];      // [d][f]
  __shared__ float sih[64 * 192];       // [d][gf] (transposed)
  __shared__ float shh[64 * 192];
  __shared__ float sbias[64 + 192 + 192];
  __shared__ float so[8][64], sm[8][64];
  int tid = threadIdx.x;
  for (int i = tid; i < 4096; i += 512) sconv[i] = convW[i];
  for (int i = tid; i < 12288; i += 512){
    int d = i / 192, gf = i % 192;
    sih[i] = Wih[gf * 64 + d];
    shh[i] = Whh[gf * 64 + d];
  }
  if (tid < 64) sbias[tid] = convB[tid];
  for (int i = tid; i < 192; i += 512){ sbias[64 + i] = bih[i]; sbias[256 + i] = bhh[i]; }
  __syncthreads();
  int wid = tid >> 6, lane = tid & 63;
  int gw = blockIdx.x * 8 + wid;        // 2048 waves total
  for (int it = 0; it < 8; it++){
    int n = it * 2048 + gw;
    float o = out[n * 64 + lane];
    so[wid][lane] = o;
    __syncthreads();
    float ic = 1.0f / fmaxf(cnt[n], 1.0f);
    float acc = aggr[n * 64 + lane] * ic + sbias[lane];
    #pragma unroll 8
    for (int d = 0; d < 64; d++) acc += so[wid][d] * sconv[d * 64 + lane];
    float m = fmaxf(acc, 0.f);
    sm[wid][lane] = m;
    __syncthreads();
    float gr = sbias[64 + lane], gz = sbias[128 + lane], gn = sbias[192 + lane];
    float hr = sbias[256 + lane], hz = sbias[320 + lane], hn = sbias[384 + lane];
    #pragma unroll 4
    for (int d = 0; d < 64; d++){
      float md = sm[wid][d], od = so[wid][d];
      const float* wi = &sih[d * 192];
      const float* wh = &shh[d * 192];
      gr += md * wi[lane];       gz += md * wi[64 + lane];  gn += md * wi[128 + lane];
      hr += od * wh[lane];       hz += od * wh[64 + lane];  hn += od * wh[128 + lane];
    }
    float r = sigm(gr + hr);
    float z = sigm(gz + hz);
    float nn = tanhf(gn + r * hn);
    out[n * 64 + lane] = (1.f - z) * nn + z * o;
    __syncthreads();
  }
}

// Set2Set LSTM step (64 threads). Also resets r_raw/esum/gmax for the coming pass.
__global__ void k_s2s_lstm(const float* __restrict__ Wih, const float* __restrict__ Whh,
    const float* __restrict__ bih, const float* __restrict__ bhh,
    float* __restrict__ scal, int first)
{
  __shared__ float q[128];
  __shared__ float hsL[64];
  int l = threadIdx.x;
  float hs = first ? 0.f : scal[l];
  float cs = first ? 0.f : scal[64 + l];
  float rv = first ? 0.f : scal[128 + l] / scal[193];
  q[l] = hs; q[64 + l] = rv; hsL[l] = hs;
  __syncthreads();
  float g[4];
  #pragma unroll
  for (int gg = 0; gg < 4; gg++){
    float a = bih[gg * 64 + l];
    const float* wr = Wih + (gg * 64 + l) * 128;
    for (int j = 0; j < 128; j++) a += q[j] * wr[j];
    float b = bhh[gg * 64 + l];
    const float* wr2 = Whh + (gg * 64 + l) * 64;
    for (int j = 0; j < 64; j++) b += hsL[j] * wr2[j];
    g[gg] = a + b;
  }
  float ig = sigm(g[0]), fg = sigm(g[1]), gv = tanhf(g[2]), og = sigm(g[3]);
  float cn = fg * cs + ig * gv;
  float hn = og * tanhf(cn);
  __syncthreads();
  scal[l] = hn; scal[64 + l] = cn; scal[128 + l] = 0.f;
  if (l == 0){ ((unsigned*)scal)[192] = 0u; scal[193] = 0.f; }
}

// s[n] = out[n,:].hs ; global max via encoded atomicMax
__global__ __launch_bounds__(256) void k_dots(const float* __restrict__ out,
    float* __restrict__ scal, float* __restrict__ sbuf)
{
  __shared__ float hsh[64];
  __shared__ float smax[4];
  int tid = threadIdx.x, wid = tid >> 6, lane = tid & 63;
  if (tid < 64) hsh[tid] = scal[tid];
  __syncthreads();
  int nbase = blockIdx.x * 256 + wid * 64;
  float hv = hsh[lane];
  float wmax = -3.4e38f;
  for (int i = 0; i < 64; i++){
    int n = nbase + i;
    float p = out[n * 64 + lane] * hv;
    p += __shfl_xor(p, 32); p += __shfl_xor(p, 16); p += __shfl_xor(p, 8);
    p += __shfl_xor(p, 4);  p += __shfl_xor(p, 2);  p += __shfl_xor(p, 1);
    if (lane == 0) sbuf[n] = p;
    wmax = fmaxf(wmax, p);
  }
  if (lane == 0) smax[wid] = wmax;
  __syncthreads();
  if (tid == 0){
    float m = fmaxf(fmaxf(smax[0], smax[1]), fmaxf(smax[2], smax[3]));
    atomicMax((unsigned*)(scal + 192), fenc(m));
  }
}

// e = exp(s - gmax); accumulate esum and r_raw = sum e_n * out[n,:]
__global__ __launch_bounds__(256) void k_sm(const float* __restrict__ out,
    const float* __restrict__ sbuf, float* __restrict__ scal)
{
  __shared__ float ebuf[256];
  __shared__ float rpart[4][64];
  int tid = threadIdx.x, wid = tid >> 6, lane = tid & 63;
  float gm = fdec(((const unsigned*)scal)[192]);
  int n = blockIdx.x * 256 + tid;
  float e = __expf(sbuf[n] - gm);
  ebuf[tid] = e;
  __syncthreads();
  int nb = blockIdx.x * 256 + wid * 64;
  float racc = 0.f;
  for (int i = 0; i < 64; i++)
    racc += ebuf[wid * 64 + i] * out[(nb + i) * 64 + lane];
  rpart[wid][lane] = racc;
  __syncthreads();
  if (wid == 0){
    float rt = rpart[0][lane] + rpart[1][lane] + rpart[2][lane] + rpart[3][lane];
    atomicAdd(&scal[128 + lane], rt);
  } else if (wid == 1){
    float es = ebuf[lane] + ebuf[64 + lane] + ebuf[128 + lane] + ebuf[192 + lane];
    es += __shfl_xor(es, 32); es += __shfl_xor(es, 16); es += __shfl_xor(es, 8);
    es += __shfl_xor(es, 4);  es += __shfl_xor(es, 2);  es += __shfl_xor(es, 1);
    if (lane == 0) atomicAdd(&scal[193], es);
  }
}

// memory LSTM + value head; writes v, hx_new, cx_new; stashes lstm_out in scal[256..]
__global__ void k_memlstm(const float* __restrict__ Wih, const float* __restrict__ Whh,
    const float* __restrict__ bih, const float* __restrict__ bhh,
    const float* __restrict__ hx, const float* __restrict__ cx,
    const float* __restrict__ W3, const float* __restrict__ b3,
    float* __restrict__ scal, float* __restrict__ dout)
{
  __shared__ float pool[128];
  __shared__ float hxs[64];
  __shared__ float lob[64];
  int l = threadIdx.x;
  pool[l] = scal[l];
  pool[64 + l] = scal[128 + l] / scal[193];
  hxs[l] = hx[l];
  __syncthreads();
  float g[4];
  #pragma unroll
  for (int gg = 0; gg < 4; gg++){
    float a = bih[gg * 64 + l];
    const float* wr = Wih + (gg * 64 + l) * 128;
    for (int j = 0; j < 128; j++) a += pool[j] * wr[j];
    float b = bhh[gg * 64 + l];
    const float* wr2 = Whh + (gg * 64 + l) * 64;
    for (int j = 0; j < 64; j++) b += hxs[j] * wr2[j];
    g[gg] = a + b;
  }
  float ig = sigm(g[0]), fg = sigm(g[1]), gv = tanhf(g[2]), og = sigm(g[3]);
  float cn = fg * cx[l] + ig * gv;
  float hn = og * tanhf(cn);
  dout[12289 + l] = hn;     // hx_new
  dout[12353 + l] = cn;     // cx_new
  scal[256 + l] = hn;       // lstm_out for head
  lob[l] = hn;
  __syncthreads();
  if (l == 0){
    float v = b3[0];
    for (int j = 0; j < 128; j++) v += pool[j] * W3[j];
    for (int j = 0; j < 64;  j++) v += lob[j] * W3[128 + j];
    dout[12288] = v;
  }
}

// torsion head. pf[t, j<256] = out[nr[j*32 + t/64], t%64]; pf[t, 256..319] = lstm_out[t>>5]
__global__ __launch_bounds__(256) void k_head(const float* __restrict__ out,
    const int* __restrict__ nr, const float* __restrict__ scal,
    const float* __restrict__ W1, const float* __restrict__ b1,
    const float* __restrict__ W2, const float* __restrict__ b2,
    float* __restrict__ dout)
{
  __shared__ float pf[4][320];
  __shared__ float hb[4][64];
  int tid = threadIdx.x, wid = tid >> 6, lane = tid & 63;
  int t = blockIdx.x * 4 + wid;
  float lo = scal[256 + (t >> 5)];
  #pragma unroll
  for (int rep = 0; rep < 4; rep++){
    int j = rep * 64 + lane;
    int idx = nr[j * 32 + (t >> 6)];
    pf[wid][j] = out[idx * 64 + (t & 63)];
  }
  pf[wid][256 + lane] = lo;
  __syncthreads();
  float acc = b1[lane];
  const float* w = W1 + lane * 320;
  #pragma unroll 4
  for (int j = 0; j < 320; j++) acc += pf[wid][j] * w[j];
  hb[wid][lane] = fmaxf(acc, 0.f);
  __syncthreads();
  if (lane < 6){
    float a2 = b2[lane];
    const float* w2 = W2 + lane * 64;
    #pragma unroll 4
    for (int f = 0; f < 64; f++) a2 += hb[wid][f] * w2[f];
    dout[t * 6 + lane] = a2;
  }
}

extern "C" void kernel_launch(void* const* d_in, const int* in_sizes, int n_in,
                              void* d_out, int out_size, void* d_ws, size_t ws_size,
                              hipStream_t stream)
{
  const float* x         = (const float*)d_in[0];
  const float* edge_attr = (const float*)d_in[1];
  const int*   ei        = (const int*)d_in[2];
  const int*   nonring   = (const int*)d_in[3];
  const float* hx        = (const float*)d_in[4];
  const float* cx        = (const float*)d_in[5];
  const float* W_lin0 = (const float*)d_in[6];  const float* b_lin0 = (const float*)d_in[7];
  const float* W_e1   = (const float*)d_in[8];  const float* b_e1   = (const float*)d_in[9];
  const float* W_e2   = (const float*)d_in[10]; const float* b_e2   = (const float*)d_in[11];
  const float* convW  = (const float*)d_in[12]; const float* convB  = (const float*)d_in[13];
  const float* gWih   = (const float*)d_in[14]; const float* gWhh   = (const float*)d_in[15];
  const float* gbih   = (const float*)d_in[16]; const float* gbhh   = (const float*)d_in[17];
  const float* sWih   = (const float*)d_in[18]; const float* sWhh   = (const float*)d_in[19];
  const float* sbih   = (const float*)d_in[20]; const float* sbhh   = (const float*)d_in[21];
  const float* mWih   = (const float*)d_in[22]; const float* mWhh   = (const float*)d_in[23];
  const float* mbih   = (const float*)d_in[24]; const float* mbhh   = (const float*)d_in[25];
  const float* W_lin1 = (const float*)d_in[26]; const float* b_lin1 = (const float*)d_in[27];
  const float* W_lin2 = (const float*)d_in[28]; const float* b_lin2 = (const float*)d_in[29];
  const float* W_lin3 = (const float*)d_in[30]; const float* b_lin3 = (const float*)d_in[31];
  float* dout = (float*)d_out;

  char* w = (char*)d_ws;
  float* outb = (float*)w;  w += (size_t)cN * 64 * 4;
  float* aggr = (float*)w;  w += (size_t)cN * 64 * 4;
  short* h1   = (short*)w;  w += (size_t)cE * 128 * 2;
  short* w2p  = (short*)w;  w += (size_t)4096 * 128 * 2;
  float* b2p  = (float*)w;  w += 4096 * 4;
  float* cntb = (float*)w;  w += cN * 4;
  float* sbuf = (float*)w;  w += cN * 4;
  float* scal = (float*)w;  w += 512 * 4;
  size_t used = (size_t)(w - (char*)d_ws);
  short* ew = (short*)w;
  size_t avail = ws_size > used ? ws_size - used : 0;
  long long chunk = (long long)(avail / 8192) & ~63LL;   // bytes per edge row = 4096*2
  if (chunk > cE) chunk = cE;
  if (chunk < 64) chunk = 64;
  int chunk_e = (int)chunk;
  bool full = (chunk_e >= cE);

  hipMemsetAsync(cntb, 0, cN * 4, stream);
  k_lin0<<<cN * 64 / 256, 256, 0, stream>>>(x, W_lin0, b_lin0, outb);
  k_h1<<<cE * 128 / 256, 256, 0, stream>>>(edge_attr, W_e1, b_e1, h1);
  k_w2perm<<<4096 * 128 / 256, 256, 0, stream>>>(W_e2, b_e2, w2p, b2p);
  k_cnt<<<cE / 256, 256, 0, stream>>>(ei, cntb);

  if (full)
    k_gemm<<<dim3(cE / 64, 16), 256, 0, stream>>>(h1, w2p, b2p, ew, 0);

  for (int it = 0; it < 3; it++){
    hipMemsetAsync(aggr, 0, (size_t)cN * 64 * 4, stream);
    if (full){
      k_msg<<<cE / 4, 256, 0, stream>>>(ew, outb, ei, aggr, 0);
    } else {
      for (int e0 = 0; e0 < cE; e0 += chunk_e){
        int n = cE - e0; if (n > chunk_e) n = chunk_e;
        k_gemm<<<dim3(n / 64, 16), 256, 0, stream>>>(h1, w2p, b2p, ew, e0);
        k_msg<<<n / 4, 256, 0, stream>>>(ew, outb, ei, aggr, e0);
      }
    }
    k_node<<<256, 512, 0, stream>>>(outb, aggr, cntb, convW, convB, gWih, gWhh, gbih, gbhh);
  }

  for (int st = 0; st < 3; st++){
    k_s2s_lstm<<<1, 64, 0, stream>>>(sWih, sWhh, sbih, sbhh, scal, st == 0 ? 1 : 0);
    k_dots<<<cN / 256, 256, 0, stream>>>(outb, scal, sbuf);
    k_sm<<<cN / 256, 256, 0, stream>>>(outb, sbuf, scal);
  }

  k_memlstm<<<1, 64, 0, stream>>>(mWih, mWhh, mbih, mbhh, hx, cx, W_lin3, b_lin3, scal, dout);
  k_head<<<cT / 4, 256, 0, stream>>>(outb, nonring, scal, W_lin1, b_lin1, W_lin2, b_lin2, dout);
}

// Round 2
// 1225.684 us; speedup vs baseline: 1.5400x; 1.5400x over previous
//
#include <hip/hip_runtime.h>

#define cN 16384
#define cE 65536
#define cT 2048

typedef __attribute__((ext_vector_type(8))) short short8;
typedef __attribute__((ext_vector_type(4))) float f32x4;

__device__ __forceinline__ short f2bf(float f){
  unsigned u = __float_as_uint(f);
  u = (u + 0x7FFFu + ((u >> 16) & 1u)) >> 16;
  return (short)u;
}
__device__ __forceinline__ float bf2f(short s){
  return __uint_as_float(((unsigned)(unsigned short)s) << 16);
}
__device__ __forceinline__ float sigm(float x){ return 1.f / (1.f + __expf(-x)); }
__device__ __forceinline__ unsigned fenc(float f){
  unsigned u = __float_as_uint(f);
  return (u & 0x80000000u) ? ~u : (u | 0x80000000u);
}
__device__ __forceinline__ float fdec(unsigned u){
  u = (u & 0x80000000u) ? (u & 0x7FFFFFFFu) : ~u;
  return __uint_as_float(u);
}

// out = relu(x @ W_lin0.T + b)
__global__ __launch_bounds__(256) void k_lin0(const float* __restrict__ x,
    const float* __restrict__ W, const float* __restrict__ b, float* __restrict__ out)
{
  int i = blockIdx.x * 256 + threadIdx.x;       // cN*64
  int n = i >> 6, f = i & 63;
  float acc = b[f] + x[n*3]*W[f*3] + x[n*3+1]*W[f*3+1] + x[n*3+2]*W[f*3+2];
  out[i] = fmaxf(acc, 0.f);
}

// h1 = bf16(relu(edge_attr @ W_e1.T + b_e1))
__global__ __launch_bounds__(256) void k_h1(const float* __restrict__ ea,
    const float* __restrict__ W, const float* __restrict__ b, short* __restrict__ h1)
{
  int i = blockIdx.x * 256 + threadIdx.x;       // cE*128
  int e = i >> 7, k = i & 127;
  const float* a = ea + e * 7;
  const float* w = W + k * 7;
  float acc = b[k];
  #pragma unroll
  for (int c = 0; c < 7; c++) acc += a[c] * w[c];
  h1[i] = f2bf(fmaxf(acc, 0.f));
}

// W2 -> fragment-major bf16 layout for the S-contraction B operand.
// Element for (fb, c, ks, lane l, j):  B[f = fb*16+(l&15)][col = c*1024+ks*32+((l>>4)&3)*8+j]
// where B[f][d*128+k] = W2[(d*64+f)*128 + k].
__global__ __launch_bounds__(256) void k_w2f(const float* __restrict__ W2, short* __restrict__ w2f)
{
  int o = blockIdx.x * 256 + threadIdx.x;       // 524288
  int j = o & 7, l = (o >> 3) & 63, ks = (o >> 9) & 31, c = (o >> 14) & 7, fb = (o >> 17) & 3;
  int col = c * 1024 + ks * 32 + ((l >> 4) & 3) * 8 + j;
  int f = fb * 16 + (l & 15);
  int d = col >> 7, k = col & 127;
  w2f[o] = f2bf(W2[d * 8192 + f * 128 + k]);
}

__global__ __launch_bounds__(256) void k_deg(const int* __restrict__ ei, int* __restrict__ deg)
{
  int e = blockIdx.x * 256 + threadIdx.x;
  atomicAdd(&deg[ei[cE + e]], 1);
}

// exclusive scan over 16384 degrees; also fills cnt = max(deg,1)
__global__ __launch_bounds__(1024) void k_scan(const int* __restrict__ deg,
    int* __restrict__ rowp, float* __restrict__ cnt)
{
  __shared__ int part[1024];
  int tid = threadIdx.x;
  int base = tid * 16;
  int loc[16]; int s = 0;
  #pragma unroll
  for (int i = 0; i < 16; i++){ loc[i] = s; s += deg[base + i]; }
  part[tid] = s;
  __syncthreads();
  for (int off = 1; off < 1024; off <<= 1){
    int v = (tid >= off) ? part[tid - off] : 0;
    __syncthreads();
    part[tid] += v;
    __syncthreads();
  }
  int inc = part[tid];
  int eb = inc - s;
  #pragma unroll
  for (int i = 0; i < 16; i++){
    rowp[base + i] = eb + loc[i];
    int dv = deg[base + i];
    cnt[base + i] = (float)(dv > 0 ? dv : 1);
  }
  if (tid == 1023) rowp[16384] = inc;
}

__global__ __launch_bounds__(256) void k_scatter(const int* __restrict__ ei,
    const int* __restrict__ rowp, int* __restrict__ cur,
    int* __restrict__ esrc, int* __restrict__ eidx)
{
  int e = blockIdx.x * 256 + threadIdx.x;
  int t = ei[cE + e];
  int pos = rowp[t] + atomicAdd(&cur[t], 1);
  esrc[pos] = ei[e];
  eidx[pos] = e;
}

// Fused bilinear aggregation:
// aggr[t,f] = sum_{d,k} S_t[d,k]*W2[(d*64+f),k] + sum_d os_t[d]*b2[d*64+f]   (raw sum; /cnt in k_node)
// Block: 16 targets, 4 waves. d-chunks of 8; S-slice [16][1024] bf16 in LDS; MFMA 16x16x32.
__global__ __launch_bounds__(256) void k_sagg(const float* __restrict__ out,
    const short* __restrict__ h1, const short* __restrict__ w2f,
    const float* __restrict__ b2, const int* __restrict__ rowp,
    const int* __restrict__ esrc, const int* __restrict__ eidx,
    float* __restrict__ aggr)
{
  __shared__ short S[16][1048];
  __shared__ float osl[16][64];
  __shared__ float b2s[4096];
  int tid = threadIdx.x, w = tid >> 6, lane = tid & 63;
  int t0 = blockIdx.x * 16;
  for (int i = tid; i < 4096; i += 256) b2s[i] = b2[i];
  f32x4 acc = {0.f, 0.f, 0.f, 0.f};
  for (int c = 0; c < 8; ++c){
    // ---- phase A: build S-slice (VGPR outer-product accumulate, then LDS write)
    for (int g = 0; g < 4; ++g){
      int ti = w * 4 + g;
      int t = t0 + ti;
      int pb = rowp[t], pe = rowp[t + 1];
      float a0[8], a1[8], osd[8];
      #pragma unroll
      for (int d = 0; d < 8; d++){ a0[d] = 0.f; a1[d] = 0.f; osd[d] = 0.f; }
      for (int p = pb; p < pe; ++p){
        int sv  = __builtin_amdgcn_readfirstlane(esrc[p]);
        int eid = __builtin_amdgcn_readfirstlane(eidx[p]);
        const float* orow = out + (size_t)sv * 64 + c * 8;
        float h1a = bf2f(h1[(size_t)eid * 128 + lane]);
        float h1b = bf2f(h1[(size_t)eid * 128 + 64 + lane]);
        #pragma unroll
        for (int d = 0; d < 8; d++){
          float o = orow[d];
          a0[d] += o * h1a; a1[d] += o * h1b; osd[d] += o;
        }
      }
      #pragma unroll
      for (int d = 0; d < 8; d++){
        S[ti][d * 128 + lane]      = f2bf(a0[d]);
        S[ti][d * 128 + 64 + lane] = f2bf(a1[d]);
      }
      if (lane == 0){
        #pragma unroll
        for (int d = 0; d < 8; d++) osl[ti][c * 8 + d] = osd[d];
      }
    }
    __syncthreads();
    // ---- phase B: MFMA contraction for this chunk (K=1024)
    int arow = lane & 15, acol = (lane >> 4) * 8;
    const short* bbase = w2f + ((size_t)(w * 8 + c) * 32) * 512 + lane * 8;
    #pragma unroll
    for (int ks = 0; ks < 32; ++ks){
      short8 afr = *(const short8*)&S[arow][acol + ks * 32];
      short8 bfr = *(const short8*)(bbase + (size_t)ks * 512);
      acc = __builtin_amdgcn_mfma_f32_16x16x32_bf16(afr, bfr, acc, 0, 0, 0);
    }
    __syncthreads();
  }
  // ---- epilogue: bias term + store raw sums
  int fcol = w * 16 + (lane & 15);
  int trow = (lane >> 4) * 4;
  #pragma unroll
  for (int q = 0; q < 4; q++){
    int ti = trow + q;
    float bias = 0.f;
    #pragma unroll 8
    for (int d = 0; d < 64; d++) bias += osl[ti][d] * b2s[d * 64 + fcol];
    aggr[(size_t)(t0 + ti) * 64 + fcol] = acc[q] + bias;
  }
}

// node update: m = relu(aggr/cnt + out@conv + cb); GRU(m, out) -> out (in place)
__global__ __launch_bounds__(512) void k_node(float* __restrict__ out,
    const float* __restrict__ aggr, const float* __restrict__ cnt,
    const float* __restrict__ convW, const float* __restrict__ convB,
    const float* __restrict__ Wih, const float* __restrict__ Whh,
    const float* __restrict__ bih, const float* __restrict__ bhh)
{
  __shared__ float sconv[64 * 64];      // [d][f]
  __shared__ float sih[64 * 192];       // [d][gf] (transposed)
  __shared__ float shh[64 * 192];
  __shared__ float sbias[64 + 192 + 192];
  __shared__ float so[8][64], sm[8][64];
  int tid = threadIdx.x;
  for (int i = tid; i < 4096; i += 512) sconv[i] = convW[i];
  for (int i = tid; i < 12288; i += 512){
    int d = i / 192, gf = i % 192;
    sih[i] = Wih[gf * 64 + d];
    shh[i] = Whh[gf * 64 + d];
  }
  if (tid < 64) sbias[tid] = convB[tid];
  for (int i = tid; i < 192; i += 512){ sbias[64 + i] = bih[i]; sbias[256 + i] = bhh[i]; }
  __syncthreads();
  int wid = tid >> 6, lane = tid & 63;
  int gw = blockIdx.x * 8 + wid;        // 2048 waves total
  for (int it = 0; it < 8; it++){
    int n = it * 2048 + gw;
    float o = out[n * 64 + lane];
    so[wid][lane] = o;
    __syncthreads();
    float ic = 1.0f / fmaxf(cnt[n], 1.0f);
    float acc = aggr[n * 64 + lane] * ic + sbias[lane];
    #pragma unroll 8
    for (int d = 0; d < 64; d++) acc += so[wid][d] * sconv[d * 64 + lane];
    float m = fmaxf(acc, 0.f);
    sm[wid][lane] = m;
    __syncthreads();
    float gr = sbias[64 + lane], gz = sbias[128 + lane], gn = sbias[192 + lane];
    float hr = sbias[256 + lane], hz = sbias[320 + lane], hn = sbias[384 + lane];
    #pragma unroll 4
    for (int d = 0; d < 64; d++){
      float md = sm[wid][d], od = so[wid][d];
      const float* wi = &sih[d * 192];
      const float* wh = &shh[d * 192];
      gr += md * wi[lane];       gz += md * wi[64 + lane];  gn += md * wi[128 + lane];
      hr += od * wh[lane];       hz += od * wh[64 + lane];  hn += od * wh[128 + lane];
    }
    float r = sigm(gr + hr);
    float z = sigm(gz + hz);
    float nn = tanhf(gn + r * hn);
    out[n * 64 + lane] = (1.f - z) * nn + z * o;
    __syncthreads();
  }
}

// Set2Set LSTM step (64 threads). Also resets r_raw/esum/gmax for the coming pass.
__global__ void k_s2s_lstm(const float* __restrict__ Wih, const float* __restrict__ Whh,
    const float* __restrict__ bih, const float* __restrict__ bhh,
    float* __restrict__ scal, int first)
{
  __shared__ float q[128];
  __shared__ float hsL[64];
  int l = threadIdx.x;
  float hs = first ? 0.f : scal[l];
  float cs = first ? 0.f : scal[64 + l];
  float rv = first ? 0.f : scal[128 + l] / scal[193];
  q[l] = hs; q[64 + l] = rv; hsL[l] = hs;
  __syncthreads();
  float g[4];
  #pragma unroll
  for (int gg = 0; gg < 4; gg++){
    float a = bih[gg * 64 + l];
    const float* wr = Wih + (gg * 64 + l) * 128;
    for (int j = 0; j < 128; j++) a += q[j] * wr[j];
    float b = bhh[gg * 64 + l];
    const float* wr2 = Whh + (gg * 64 + l) * 64;
    for (int j = 0; j < 64; j++) b += hsL[j] * wr2[j];
    g[gg] = a + b;
  }
  float ig = sigm(g[0]), fg = sigm(g[1]), gv = tanhf(g[2]), og = sigm(g[3]);
  float cn = fg * cs + ig * gv;
  float hn = og * tanhf(cn);
  __syncthreads();
  scal[l] = hn; scal[64 + l] = cn; scal[128 + l] = 0.f;
  if (l == 0){ ((unsigned*)scal)[192] = 0u; scal[193] = 0.f; }
}

// s[n] = out[n,:].hs ; global max via encoded atomicMax
__global__ __launch_bounds__(256) void k_dots(const float* __restrict__ out,
    float* __restrict__ scal, float* __restrict__ sbuf)
{
  __shared__ float hsh[64];
  __shared__ float smax[4];
  int tid = threadIdx.x, wid = tid >> 6, lane = tid & 63;
  if (tid < 64) hsh[tid] = scal[tid];
  __syncthreads();
  int nbase = blockIdx.x * 256 + wid * 64;
  float hv = hsh[lane];
  float wmax = -3.4e38f;
  for (int i = 0; i < 64; i++){
    int n = nbase + i;
    float p = out[n * 64 + lane] * hv;
    p += __shfl_xor(p, 32); p += __shfl_xor(p, 16); p += __shfl_xor(p, 8);
    p += __shfl_xor(p, 4);  p += __shfl_xor(p, 2);  p += __shfl_xor(p, 1);
    if (lane == 0) sbuf[n] = p;
    wmax = fmaxf(wmax, p);
  }
  if (lane == 0) smax[wid] = wmax;
  __syncthreads();
  if (tid == 0){
    float m = fmaxf(fmaxf(smax[0], smax[1]), fmaxf(smax[2], smax[3]));
    atomicMax((unsigned*)(scal + 192), fenc(m));
  }
}

// e = exp(s - gmax); accumulate esum and r_raw = sum e_n * out[n,:]
__global__ __launch_bounds__(256) void k_sm(const float* __restrict__ out,
    const float* __restrict__ sbuf, float* __restrict__ scal)
{
  __shared__ float ebuf[256];
  __shared__ float rpart[4][64];
  int tid = threadIdx.x, wid = tid >> 6, lane = tid & 63;
  float gm = fdec(((const unsigned*)scal)[192]);
  int n = blockIdx.x * 256 + tid;
  float e = __expf(sbuf[n] - gm);
  ebuf[tid] = e;
  __syncthreads();
  int nb = blockIdx.x * 256 + wid * 64;
  float racc = 0.f;
  for (int i = 0; i < 64; i++)
    racc += ebuf[wid * 64 + i] * out[(nb + i) * 64 + lane];
  rpart[wid][lane] = racc;
  __syncthreads();
  if (wid == 0){
    float rt = rpart[0][lane] + rpart[1][lane] + rpart[2][lane] + rpart[3][lane];
    atomicAdd(&scal[128 + lane], rt);
  } else if (wid == 1){
    float es = ebuf[lane] + ebuf[64 + lane] + ebuf[128 + lane] + ebuf[192 + lane];
    es += __shfl_xor(es, 32); es += __shfl_xor(es, 16); es += __shfl_xor(es, 8);
    es += __shfl_xor(es, 4);  es += __shfl_xor(es, 2);  es += __shfl_xor(es, 1);
    if (lane == 0) atomicAdd(&scal[193], es);
  }
}

// memory LSTM + value head; writes v, hx_new, cx_new; stashes lstm_out in scal[256..]
__global__ void k_memlstm(const float* __restrict__ Wih, const float* __restrict__ Whh,
    const float* __restrict__ bih, const float* __restrict__ bhh,
    const float* __restrict__ hx, const float* __restrict__ cx,
    const float* __restrict__ W3, const float* __restrict__ b3,
    float* __restrict__ scal, float* __restrict__ dout)
{
  __shared__ float pool[128];
  __shared__ float hxs[64];
  __shared__ float lob[64];
  int l = threadIdx.x;
  pool[l] = scal[l];
  pool[64 + l] = scal[128 + l] / scal[193];
  hxs[l] = hx[l];
  __syncthreads();
  float g[4];
  #pragma unroll
  for (int gg = 0; gg < 4; gg++){
    float a = bih[gg * 64 + l];
    const float* wr = Wih + (gg * 64 + l) * 128;
    for (int j = 0; j < 128; j++) a += pool[j] * wr[j];
    float b = bhh[gg * 64 + l];
    const float* wr2 = Whh + (gg * 64 + l) * 64;
    for (int j = 0; j < 64; j++) b += hxs[j] * wr2[j];
    g[gg] = a + b;
  }
  float ig = sigm(g[0]), fg = sigm(g[1]), gv = tanhf(g[2]), og = sigm(g[3]);
  float cn = fg * cx[l] + ig * gv;
  float hn = og * tanhf(cn);
  dout[12289 + l] = hn;     // hx_new
  dout[12353 + l] = cn;     // cx_new
  scal[256 + l] = hn;       // lstm_out for head
  lob[l] = hn;
  __syncthreads();
  if (l == 0){
    float v = b3[0];
    for (int j = 0; j < 128; j++) v += pool[j] * W3[j];
    for (int j = 0; j < 64;  j++) v += lob[j] * W3[128 + j];
    dout[12288] = v;
  }
}

// torsion head. pf[t, j<256] = out[nr[j*32 + t/64], t%64]; pf[t, 256..319] = lstm_out[t>>5]
__global__ __launch_bounds__(256) void k_head(const float* __restrict__ out,
    const int* __restrict__ nr, const float* __restrict__ scal,
    const float* __restrict__ W1, const float* __restrict__ b1,
    const float* __restrict__ W2, const float* __restrict__ b2,
    float* __restrict__ dout)
{
  __shared__ float pf[4][320];
  __shared__ float hb[4][64];
  int tid = threadIdx.x, wid = tid >> 6, lane = tid & 63;
  int t = blockIdx.x * 4 + wid;
  float lo = scal[256 + (t >> 5)];
  #pragma unroll
  for (int rep = 0; rep < 4; rep++){
    int j = rep * 64 + lane;
    int idx = nr[j * 32 + (t >> 6)];
    pf[wid][j] = out[idx * 64 + (t & 63)];
  }
  pf[wid][256 + lane] = lo;
  __syncthreads();
  float acc = b1[lane];
  const float* w = W1 + lane * 320;
  #pragma unroll 4
  for (int j = 0; j < 320; j++) acc += pf[wid][j] * w[j];
  hb[wid][lane] = fmaxf(acc, 0.f);
  __syncthreads();
  if (lane < 6){
    float a2 = b2[lane];
    const float* w2 = W2 + lane * 64;
    #pragma unroll 4
    for (int f = 0; f < 64; f++) a2 += hb[wid][f] * w2[f];
    dout[t * 6 + lane] = a2;
  }
}

extern "C" void kernel_launch(void* const* d_in, const int* in_sizes, int n_in,
                              void* d_out, int out_size, void* d_ws, size_t ws_size,
                              hipStream_t stream)
{
  const float* x         = (const float*)d_in[0];
  const float* edge_attr = (const float*)d_in[1];
  const int*   ei        = (const int*)d_in[2];
  const int*   nonring   = (const int*)d_in[3];
  const float* hx        = (const float*)d_in[4];
  const float* cx        = (const float*)d_in[5];
  const float* W_lin0 = (const float*)d_in[6];  const float* b_lin0 = (const float*)d_in[7];
  const float* W_e1   = (const float*)d_in[8];  const float* b_e1   = (const float*)d_in[9];
  const float* W_e2   = (const float*)d_in[10]; const float* b_e2   = (const float*)d_in[11];
  const float* convW  = (const float*)d_in[12]; const float* convB  = (const float*)d_in[13];
  const float* gWih   = (const float*)d_in[14]; const float* gWhh   = (const float*)d_in[15];
  const float* gbih   = (const float*)d_in[16]; const float* gbhh   = (const float*)d_in[17];
  const float* sWih   = (const float*)d_in[18]; const float* sWhh   = (const float*)d_in[19];
  const float* sbih   = (const float*)d_in[20]; const float* sbhh   = (const float*)d_in[21];
  const float* mWih   = (const float*)d_in[22]; const float* mWhh   = (const float*)d_in[23];
  const float* mbih   = (const float*)d_in[24]; const float* mbhh   = (const float*)d_in[25];
  const float* W_lin1 = (const float*)d_in[26]; const float* b_lin1 = (const float*)d_in[27];
  const float* W_lin2 = (const float*)d_in[28]; const float* b_lin2 = (const float*)d_in[29];
  const float* W_lin3 = (const float*)d_in[30]; const float* b_lin3 = (const float*)d_in[31];
  float* dout = (float*)d_out;

  char* w = (char*)d_ws;
  float* outb = (float*)w;  w += (size_t)cN * 64 * 4;
  float* aggr = (float*)w;  w += (size_t)cN * 64 * 4;
  short* h1   = (short*)w;  w += (size_t)cE * 128 * 2;
  short* w2f  = (short*)w;  w += (size_t)64 * 8192 * 2;
  float* cntb = (float*)w;  w += cN * 4;
  float* sbuf = (float*)w;  w += cN * 4;
  float* scal = (float*)w;  w += 512 * 4;
  int* deg  = (int*)w;  w += cN * 4;
  int* cur  = (int*)w;  w += cN * 4;
  int* rowp = (int*)w;  w += (cN + 1) * 4 + 60;   // keep alignment
  int* esrc = (int*)w;  w += cE * 4;
  int* eidx = (int*)w;  w += cE * 4;

  hipMemsetAsync(deg, 0, cN * 4, stream);
  hipMemsetAsync(cur, 0, cN * 4, stream);

  k_lin0<<<cN * 64 / 256, 256, 0, stream>>>(x, W_lin0, b_lin0, outb);
  k_h1<<<cE * 128 / 256, 256, 0, stream>>>(edge_attr, W_e1, b_e1, h1);
  k_w2f<<<64 * 8192 / 256, 256, 0, stream>>>(W_e2, w2f);
  k_deg<<<cE / 256, 256, 0, stream>>>(ei, deg);
  k_scan<<<1, 1024, 0, stream>>>(deg, rowp, cntb);
  k_scatter<<<cE / 256, 256, 0, stream>>>(ei, rowp, cur, esrc, eidx);

  for (int it = 0; it < 3; it++){
    k_sagg<<<cN / 16, 256, 0, stream>>>(outb, h1, w2f, b_e2, rowp, esrc, eidx, aggr);
    k_node<<<256, 512, 0, stream>>>(outb, aggr, cntb, convW, convB, gWih, gWhh, gbih, gbhh);
  }

  for (int st = 0; st < 3; st++){
    k_s2s_lstm<<<1, 64, 0, stream>>>(sWih, sWhh, sbih, sbhh, scal, st == 0 ? 1 : 0);
    k_dots<<<cN / 256, 256, 0, stream>>>(outb, scal, sbuf);
    k_sm<<<cN / 256, 256, 0, stream>>>(outb, sbuf, scal);
  }

  k_memlstm<<<1, 64, 0, stream>>>(mWih, mWhh, mbih, mbhh, hx, cx, W_lin3, b_lin3, scal, dout);
  k_head<<<cT / 4, 256, 0, stream>>>(outb, nonring, scal, W_lin1, b_lin1, W_lin2, b_lin2, dout);
}

// Round 3
// 1021.352 us; speedup vs baseline: 1.8480x; 1.2001x over previous
//
#include <hip/hip_runtime.h>

#define cN 16384
#define cE 65536
#define cT 2048
#define CAP 104

typedef __attribute__((ext_vector_type(8))) short short8;
typedef __attribute__((ext_vector_type(4))) float f32x4;

__device__ __forceinline__ short f2bf(float f){
  unsigned u = __float_as_uint(f);
  u = (u + 0x7FFFu + ((u >> 16) & 1u)) >> 16;
  return (short)u;
}
__device__ __forceinline__ float bf2f(short s){
  return __uint_as_float(((unsigned)(unsigned short)s) << 16);
}
__device__ __forceinline__ float sigm(float x){ return 1.f / (1.f + __expf(-x)); }
__device__ __forceinline__ unsigned fenc(float f){
  unsigned u = __float_as_uint(f);
  return (u & 0x80000000u) ? ~u : (u | 0x80000000u);
}
__device__ __forceinline__ float fdec(unsigned u){
  u = (u & 0x80000000u) ? (u & 0x7FFFFFFFu) : ~u;
  return __uint_as_float(u);
}

// out = relu(x @ W_lin0.T + b)
__global__ __launch_bounds__(256) void k_lin0(const float* __restrict__ x,
    const float* __restrict__ W, const float* __restrict__ b, float* __restrict__ out)
{
  int i = blockIdx.x * 256 + threadIdx.x;       // cN*64
  int n = i >> 6, f = i & 63;
  float acc = b[f] + x[n*3]*W[f*3] + x[n*3+1]*W[f*3+1] + x[n*3+2]*W[f*3+2];
  out[i] = fmaxf(acc, 0.f);
}

// h1 = bf16(relu(edge_attr @ W_e1.T + b_e1))
__global__ __launch_bounds__(256) void k_h1(const float* __restrict__ ea,
    const float* __restrict__ W, const float* __restrict__ b, short* __restrict__ h1)
{
  int i = blockIdx.x * 256 + threadIdx.x;       // cE*128
  int e = i >> 7, k = i & 127;
  const float* a = ea + e * 7;
  const float* w = W + k * 7;
  float acc = b[k];
  #pragma unroll
  for (int c = 0; c < 7; c++) acc += a[c] * w[c];
  h1[i] = f2bf(fmaxf(acc, 0.f));
}

// W2 -> fragment-major bf16 layout for the S-contraction B operand.
__global__ __launch_bounds__(256) void k_w2f(const float* __restrict__ W2, short* __restrict__ w2f)
{
  int o = blockIdx.x * 256 + threadIdx.x;       // 524288
  int j = o & 7, l = (o >> 3) & 63, ks = (o >> 9) & 31, c = (o >> 14) & 7, fb = (o >> 17) & 3;
  int col = c * 1024 + ks * 32 + ((l >> 4) & 3) * 8 + j;
  int f = fb * 16 + (l & 15);
  int d = col >> 7, k = col & 127;
  w2f[o] = f2bf(W2[d * 8192 + f * 128 + k]);
}

// b2 -> B-fragment layout for the bias MFMA: (fb, ks2, l, j) -> b2[d*64+f],
// d = ks2*32 + ((l>>4)&3)*8 + j, f = fb*16 + (l&15). 4096 elems.
__global__ __launch_bounds__(256) void k_b2f(const float* __restrict__ b2, short* __restrict__ b2f)
{
  int o = blockIdx.x * 256 + threadIdx.x;       // 4096
  int j = o & 7, l = (o >> 3) & 63, ks2 = (o >> 9) & 1, fb = (o >> 10) & 3;
  int d = ks2 * 32 + ((l >> 4) & 3) * 8 + j;
  int f = fb * 16 + (l & 15);
  b2f[o] = f2bf(b2[d * 64 + f]);
}

__global__ __launch_bounds__(256) void k_deg(const int* __restrict__ ei, int* __restrict__ deg)
{
  int e = blockIdx.x * 256 + threadIdx.x;
  atomicAdd(&deg[ei[cE + e]], 1);
}

// exclusive scan over 16384 degrees; also fills cnt = max(deg,1)
__global__ __launch_bounds__(1024) void k_scan(const int* __restrict__ deg,
    int* __restrict__ rowp, float* __restrict__ cnt)
{
  __shared__ int part[1024];
  int tid = threadIdx.x;
  int base = tid * 16;
  int loc[16]; int s = 0;
  #pragma unroll
  for (int i = 0; i < 16; i++){ loc[i] = s; s += deg[base + i]; }
  part[tid] = s;
  __syncthreads();
  for (int off = 1; off < 1024; off <<= 1){
    int v = (tid >= off) ? part[tid - off] : 0;
    __syncthreads();
    part[tid] += v;
    __syncthreads();
  }
  int inc = part[tid];
  int eb = inc - s;
  #pragma unroll
  for (int i = 0; i < 16; i++){
    rowp[base + i] = eb + loc[i];
    int dv = deg[base + i];
    cnt[base + i] = (float)(dv > 0 ? dv : 1);
  }
  if (tid == 1023) rowp[16384] = inc;
}

__global__ __launch_bounds__(256) void k_scatter(const int* __restrict__ ei,
    const int* __restrict__ rowp, int* __restrict__ cur,
    int* __restrict__ esrc, int* __restrict__ eidx)
{
  int e = blockIdx.x * 256 + threadIdx.x;
  int t = ei[cE + e];
  int pos = rowp[t] + atomicAdd(&cur[t], 1);
  esrc[pos] = ei[e];
  eidx[pos] = e;
}

// Fused bilinear aggregation with LDS-staged edge data.
// aggr[t,f] = sum_{d,k} S_t[d,k]*W2'[f][d,k] + sum_d os_t[d]*b2[d*64+f]  (raw; /cnt in k_node)
__global__ __launch_bounds__(256) void k_sagg(const float* __restrict__ out,
    const short* __restrict__ h1, const short* __restrict__ w2f,
    const short* __restrict__ b2f, const int* __restrict__ rowp,
    const int* __restrict__ esrc, const int* __restrict__ eidx,
    float* __restrict__ aggr)
{
  __shared__ __align__(16) short S[16][1056];     // stride%128B==64 -> uniform bank spread
  __shared__ __align__(16) short h1s[CAP][128];
  __shared__ __align__(16) short outs[CAP][64];
  __shared__ __align__(16) short osb[16][72];
  int tid = threadIdx.x, w = tid >> 6, lane = tid & 63;
  int t0 = blockIdx.x * 16;

  int ebase = rowp[t0];
  int eend  = rowp[t0 + 16];
  int ecnt  = eend - ebase;
  int scnt  = ecnt < CAP ? ecnt : CAP;
  // ---- stage edge data once (coalesced) ----
  for (int i = w; i < scnt; i += 4){
    int eid = eidx[ebase + i];
    int src = esrc[ebase + i];
    h1s[i][lane]      = h1[(size_t)eid * 128 + lane];
    h1s[i][64 + lane] = h1[(size_t)eid * 128 + 64 + lane];
    outs[i][lane]     = f2bf(out[(size_t)src * 64 + lane]);
  }
  // per-wave target slices
  int toff[4], tcnt[4];
  #pragma unroll
  for (int g = 0; g < 4; g++){
    int t = t0 + w * 4 + g;
    int a = rowp[t], b = rowp[t + 1];
    toff[g] = a - ebase; tcnt[g] = b - a;
  }
  __syncthreads();

  f32x4 acc = {0.f, 0.f, 0.f, 0.f};
  int arow = lane & 15, kg = lane >> 4;
  for (int c = 0; c < 8; ++c){
    // ---- phase A: build S-slice from LDS-staged data ----
    #pragma unroll
    for (int g = 0; g < 4; ++g){
      int ti = w * 4 + g;
      float a0[8], a1[8], osd[8];
      #pragma unroll
      for (int d = 0; d < 8; d++){ a0[d] = 0.f; a1[d] = 0.f; osd[d] = 0.f; }
      int tc = tcnt[g], tf = toff[g];
      for (int p = 0; p < tc; ++p){
        int slot = tf + p;
        if (slot < CAP){
          float h1a = bf2f(h1s[slot][lane]);
          float h1b = bf2f(h1s[slot][64 + lane]);
          short8 ov = *(const short8*)&outs[slot][c * 8];
          #pragma unroll
          for (int d = 0; d < 8; d++){
            float o = bf2f(ov[d]);
            a0[d] += o * h1a; a1[d] += o * h1b; osd[d] += o;
          }
        } else {  // overflow fallback (rare): direct global reads
          int eid = eidx[ebase + slot];
          int src = esrc[ebase + slot];
          float h1a = bf2f(h1[(size_t)eid * 128 + lane]);
          float h1b = bf2f(h1[(size_t)eid * 128 + 64 + lane]);
          #pragma unroll
          for (int d = 0; d < 8; d++){
            float o = out[(size_t)src * 64 + c * 8 + d];
            a0[d] += o * h1a; a1[d] += o * h1b; osd[d] += o;
          }
        }
      }
      #pragma unroll
      for (int d = 0; d < 8; d++){
        S[ti][d * 128 + lane]      = f2bf(a0[d]);
        S[ti][d * 128 + 64 + lane] = f2bf(a1[d]);
      }
      if (lane == 0){
        #pragma unroll
        for (int d = 0; d < 8; d++) osb[ti][c * 8 + d] = f2bf(osd[d]);
      }
    }
    __syncthreads();
    // ---- phase B: MFMA contraction for this chunk (K=1024) ----
    const short* bbase = w2f + ((size_t)(w * 8 + c) * 32) * 512 + lane * 8;
    #pragma unroll
    for (int ks = 0; ks < 32; ++ks){
      short8 afr = *(const short8*)&S[arow][kg * 8 + ks * 32];
      short8 bfr = *(const short8*)(bbase + (size_t)ks * 512);
      acc = __builtin_amdgcn_mfma_f32_16x16x32_bf16(afr, bfr, acc, 0, 0, 0);
    }
    __syncthreads();
  }
  // ---- bias term as 2 MFMA steps: acc += os @ B2 ----
  #pragma unroll
  for (int ks2 = 0; ks2 < 2; ++ks2){
    short8 osf = *(const short8*)&osb[arow][ks2 * 32 + kg * 8];
    short8 bfr = *(const short8*)(b2f + ((size_t)((w * 2 + ks2) * 64 + lane)) * 8);
    acc = __builtin_amdgcn_mfma_f32_16x16x32_bf16(osf, bfr, acc, 0, 0, 0);
  }
  // ---- store raw sums ----
  int fcol = w * 16 + arow;
  int trow = kg * 4;
  #pragma unroll
  for (int q = 0; q < 4; q++)
    aggr[(size_t)(t0 + trow + q) * 64 + fcol] = acc[q];
}

// node update: m = relu(aggr/cnt + out@conv + cb); GRU(m, out) -> out (in place)
__global__ __launch_bounds__(512) void k_node(float* __restrict__ out,
    const float* __restrict__ aggr, const float* __restrict__ cnt,
    const float* __restrict__ convW, const float* __restrict__ convB,
    const float* __restrict__ Wih, const float* __restrict__ Whh,
    const float* __restrict__ bih, const float* __restrict__ bhh)
{
  __shared__ float sconv[64 * 64];      // [d][f]
  __shared__ float sih[64 * 192];       // [d][gf] (transposed)
  __shared__ float shh[64 * 192];
  __shared__ float sbias[64 + 192 + 192];
  __shared__ float so[8][64], sm[8][64];
  int tid = threadIdx.x;
  for (int i = tid; i < 4096; i += 512) sconv[i] = convW[i];
  for (int i = tid; i < 12288; i += 512){
    int d = i / 192, gf = i % 192;
    sih[i] = Wih[gf * 64 + d];
    shh[i] = Whh[gf * 64 + d];
  }
  if (tid < 64) sbias[tid] = convB[tid];
  for (int i = tid; i < 192; i += 512){ sbias[64 + i] = bih[i]; sbias[256 + i] = bhh[i]; }
  __syncthreads();
  int wid = tid >> 6, lane = tid & 63;
  int gw = blockIdx.x * 8 + wid;        // 2048 waves total
  for (int it = 0; it < 8; it++){
    int n = it * 2048 + gw;
    float o = out[n * 64 + lane];
    so[wid][lane] = o;
    __syncthreads();
    float ic = 1.0f / fmaxf(cnt[n], 1.0f);
    float acc = aggr[n * 64 + lane] * ic + sbias[lane];
    #pragma unroll 8
    for (int d = 0; d < 64; d++) acc += so[wid][d] * sconv[d * 64 + lane];
    float m = fmaxf(acc, 0.f);
    sm[wid][lane] = m;
    __syncthreads();
    float gr = sbias[64 + lane], gz = sbias[128 + lane], gn = sbias[192 + lane];
    float hr = sbias[256 + lane], hz = sbias[320 + lane], hn = sbias[384 + lane];
    #pragma unroll 4
    for (int d = 0; d < 64; d++){
      float md = sm[wid][d], od = so[wid][d];
      const float* wi = &sih[d * 192];
      const float* wh = &shh[d * 192];
      gr += md * wi[lane];       gz += md * wi[64 + lane];  gn += md * wi[128 + lane];
      hr += od * wh[lane];       hz += od * wh[64 + lane];  hn += od * wh[128 + lane];
    }
    float r = sigm(gr + hr);
    float z = sigm(gz + hz);
    float nn = tanhf(gn + r * hn);
    out[n * 64 + lane] = (1.f - z) * nn + z * o;
    __syncthreads();
  }
}

// Set2Set LSTM step (64 threads). Also resets r_raw/esum/gmax for the coming pass.
__global__ void k_s2s_lstm(const float* __restrict__ Wih, const float* __restrict__ Whh,
    const float* __restrict__ bih, const float* __restrict__ bhh,
    float* __restrict__ scal, int first)
{
  __shared__ float q[128];
  __shared__ float hsL[64];
  int l = threadIdx.x;
  float hs = first ? 0.f : scal[l];
  float cs = first ? 0.f : scal[64 + l];
  float rv = first ? 0.f : scal[128 + l] / scal[193];
  q[l] = hs; q[64 + l] = rv; hsL[l] = hs;
  __syncthreads();
  float g[4];
  #pragma unroll
  for (int gg = 0; gg < 4; gg++){
    float a = bih[gg * 64 + l];
    const float* wr = Wih + (gg * 64 + l) * 128;
    for (int j = 0; j < 128; j++) a += q[j] * wr[j];
    float b = bhh[gg * 64 + l];
    const float* wr2 = Whh + (gg * 64 + l) * 64;
    for (int j = 0; j < 64; j++) b += hsL[j] * wr2[j];
    g[gg] = a + b;
  }
  float ig = sigm(g[0]), fg = sigm(g[1]), gv = tanhf(g[2]), og = sigm(g[3]);
  float cn = fg * cs + ig * gv;
  float hn = og * tanhf(cn);
  __syncthreads();
  scal[l] = hn; scal[64 + l] = cn; scal[128 + l] = 0.f;
  if (l == 0){ ((unsigned*)scal)[192] = 0u; scal[193] = 0.f; }
}

// s[n] = out[n,:].hs ; global max via encoded atomicMax
__global__ __launch_bounds__(256) void k_dots(const float* __restrict__ out,
    float* __restrict__ scal, float* __restrict__ sbuf)
{
  __shared__ float hsh[64];
  __shared__ float smax[4];
  int tid = threadIdx.x, wid = tid >> 6, lane = tid & 63;
  if (tid < 64) hsh[tid] = scal[tid];
  __syncthreads();
  int nbase = blockIdx.x * 256 + wid * 64;
  float hv = hsh[lane];
  float wmax = -3.4e38f;
  for (int i = 0; i < 64; i++){
    int n = nbase + i;
    float p = out[n * 64 + lane] * hv;
    p += __shfl_xor(p, 32); p += __shfl_xor(p, 16); p += __shfl_xor(p, 8);
    p += __shfl_xor(p, 4);  p += __shfl_xor(p, 2);  p += __shfl_xor(p, 1);
    if (lane == 0) sbuf[n] = p;
    wmax = fmaxf(wmax, p);
  }
  if (lane == 0) smax[wid] = wmax;
  __syncthreads();
  if (tid == 0){
    float m = fmaxf(fmaxf(smax[0], smax[1]), fmaxf(smax[2], smax[3]));
    atomicMax((unsigned*)(scal + 192), fenc(m));
  }
}

// e = exp(s - gmax); accumulate esum and r_raw = sum e_n * out[n,:]
__global__ __launch_bounds__(256) void k_sm(const float* __restrict__ out,
    const float* __restrict__ sbuf, float* __restrict__ scal)
{
  __shared__ float ebuf[256];
  __shared__ float rpart[4][64];
  int tid = threadIdx.x, wid = tid >> 6, lane = tid & 63;
  float gm = fdec(((const unsigned*)scal)[192]);
  int n = blockIdx.x * 256 + tid;
  float e = __expf(sbuf[n] - gm);
  ebuf[tid] = e;
  __syncthreads();
  int nb = blockIdx.x * 256 + wid * 64;
  float racc = 0.f;
  for (int i = 0; i < 64; i++)
    racc += ebuf[wid * 64 + i] * out[(nb + i) * 64 + lane];
  rpart[wid][lane] = racc;
  __syncthreads();
  if (wid == 0){
    float rt = rpart[0][lane] + rpart[1][lane] + rpart[2][lane] + rpart[3][lane];
    atomicAdd(&scal[128 + lane], rt);
  } else if (wid == 1){
    float es = ebuf[lane] + ebuf[64 + lane] + ebuf[128 + lane] + ebuf[192 + lane];
    es += __shfl_xor(es, 32); es += __shfl_xor(es, 16); es += __shfl_xor(es, 8);
    es += __shfl_xor(es, 4);  es += __shfl_xor(es, 2);  es += __shfl_xor(es, 1);
    if (lane == 0) atomicAdd(&scal[193], es);
  }
}

// memory LSTM + value head; writes v, hx_new, cx_new; stashes lstm_out in scal[256..]
__global__ void k_memlstm(const float* __restrict__ Wih, const float* __restrict__ Whh,
    const float* __restrict__ bih, const float* __restrict__ bhh,
    const float* __restrict__ hx, const float* __restrict__ cx,
    const float* __restrict__ W3, const float* __restrict__ b3,
    float* __restrict__ scal, float* __restrict__ dout)
{
  __shared__ float pool[128];
  __shared__ float hxs[64];
  __shared__ float lob[64];
  int l = threadIdx.x;
  pool[l] = scal[l];
  pool[64 + l] = scal[128 + l] / scal[193];
  hxs[l] = hx[l];
  __syncthreads();
  float g[4];
  #pragma unroll
  for (int gg = 0; gg < 4; gg++){
    float a = bih[gg * 64 + l];
    const float* wr = Wih + (gg * 64 + l) * 128;
    for (int j = 0; j < 128; j++) a += pool[j] * wr[j];
    float b = bhh[gg * 64 + l];
    const float* wr2 = Whh + (gg * 64 + l) * 64;
    for (int j = 0; j < 64; j++) b += hxs[j] * wr2[j];
    g[gg] = a + b;
  }
  float ig = sigm(g[0]), fg = sigm(g[1]), gv = tanhf(g[2]), og = sigm(g[3]);
  float cn = fg * cx[l] + ig * gv;
  float hn = og * tanhf(cn);
  dout[12289 + l] = hn;     // hx_new
  dout[12353 + l] = cn;     // cx_new
  scal[256 + l] = hn;       // lstm_out for head
  lob[l] = hn;
  __syncthreads();
  if (l == 0){
    float v = b3[0];
    for (int j = 0; j < 128; j++) v += pool[j] * W3[j];
    for (int j = 0; j < 64;  j++) v += lob[j] * W3[128 + j];
    dout[12288] = v;
  }
}

// torsion head. pf[t, j<256] = out[nr[j*32 + t/64], t%64]; pf[t, 256..319] = lstm_out[t>>5]
__global__ __launch_bounds__(256) void k_head(const float* __restrict__ out,
    const int* __restrict__ nr, const float* __restrict__ scal,
    const float* __restrict__ W1, const float* __restrict__ b1,
    const float* __restrict__ W2, const float* __restrict__ b2,
    float* __restrict__ dout)
{
  __shared__ float pf[4][320];
  __shared__ float hb[4][64];
  int tid = threadIdx.x, wid = tid >> 6, lane = tid & 63;
  int t = blockIdx.x * 4 + wid;
  float lo = scal[256 + (t >> 5)];
  #pragma unroll
  for (int rep = 0; rep < 4; rep++){
    int j = rep * 64 + lane;
    int idx = nr[j * 32 + (t >> 6)];
    pf[wid][j] = out[idx * 64 + (t & 63)];
  }
  pf[wid][256 + lane] = lo;
  __syncthreads();
  float acc = b1[lane];
  const float* w = W1 + lane * 320;
  #pragma unroll 4
  for (int j = 0; j < 320; j++) acc += pf[wid][j] * w[j];
  hb[wid][lane] = fmaxf(acc, 0.f);
  __syncthreads();
  if (lane < 6){
    float a2 = b2[lane];
    const float* w2 = W2 + lane * 64;
    #pragma unroll 4
    for (int f = 0; f < 64; f++) a2 += hb[wid][f] * w2[f];
    dout[t * 6 + lane] = a2;
  }
}

extern "C" void kernel_launch(void* const* d_in, const int* in_sizes, int n_in,
                              void* d_out, int out_size, void* d_ws, size_t ws_size,
                              hipStream_t stream)
{
  const float* x         = (const float*)d_in[0];
  const float* edge_attr = (const float*)d_in[1];
  const int*   ei        = (const int*)d_in[2];
  const int*   nonring   = (const int*)d_in[3];
  const float* hx        = (const float*)d_in[4];
  const float* cx        = (const float*)d_in[5];
  const float* W_lin0 = (const float*)d_in[6];  const float* b_lin0 = (const float*)d_in[7];
  const float* W_e1   = (const float*)d_in[8];  const float* b_e1   = (const float*)d_in[9];
  const float* W_e2   = (const float*)d_in[10]; const float* b_e2   = (const float*)d_in[11];
  const float* convW  = (const float*)d_in[12]; const float* convB  = (const float*)d_in[13];
  const float* gWih   = (const float*)d_in[14]; const float* gWhh   = (const float*)d_in[15];
  const float* gbih   = (const float*)d_in[16]; const float* gbhh   = (const float*)d_in[17];
  const float* sWih   = (const float*)d_in[18]; const float* sWhh   = (const float*)d_in[19];
  const float* sbih   = (const float*)d_in[20]; const float* sbhh   = (const float*)d_in[21];
  const float* mWih   = (const float*)d_in[22]; const float* mWhh   = (const float*)d_in[23];
  const float* mbih   = (const float*)d_in[24]; const float* mbhh   = (const float*)d_in[25];
  const float* W_lin1 = (const float*)d_in[26]; const float* b_lin1 = (const float*)d_in[27];
  const float* W_lin2 = (const float*)d_in[28]; const float* b_lin2 = (const float*)d_in[29];
  const float* W_lin3 = (const float*)d_in[30]; const float* b_lin3 = (const float*)d_in[31];
  float* dout = (float*)d_out;

  char* w = (char*)d_ws;
  float* outb = (float*)w;  w += (size_t)cN * 64 * 4;
  float* aggr = (float*)w;  w += (size_t)cN * 64 * 4;
  short* h1   = (short*)w;  w += (size_t)cE * 128 * 2;
  short* w2f  = (short*)w;  w += (size_t)64 * 8192 * 2;
  short* b2f  = (short*)w;  w += 4096 * 2;
  float* cntb = (float*)w;  w += cN * 4;
  float* sbuf = (float*)w;  w += cN * 4;
  float* scal = (float*)w;  w += 512 * 4;
  int* deg  = (int*)w;  w += cN * 4;
  int* cur  = (int*)w;  w += cN * 4;
  int* rowp = (int*)w;  w += (cN + 1) * 4 + 60;   // keep alignment
  int* esrc = (int*)w;  w += cE * 4;
  int* eidx = (int*)w;  w += cE * 4;

  hipMemsetAsync(deg, 0, cN * 4, stream);
  hipMemsetAsync(cur, 0, cN * 4, stream);

  k_lin0<<<cN * 64 / 256, 256, 0, stream>>>(x, W_lin0, b_lin0, outb);
  k_h1<<<cE * 128 / 256, 256, 0, stream>>>(edge_attr, W_e1, b_e1, h1);
  k_w2f<<<64 * 8192 / 256, 256, 0, stream>>>(W_e2, w2f);
  k_b2f<<<16, 256, 0, stream>>>(b_e2, b2f);
  k_deg<<<cE / 256, 256, 0, stream>>>(ei, deg);
  k_scan<<<1, 1024, 0, stream>>>(deg, rowp, cntb);
  k_scatter<<<cE / 256, 256, 0, stream>>>(ei, rowp, cur, esrc, eidx);

  for (int it = 0; it < 3; it++){
    k_sagg<<<cN / 16, 256, 0, stream>>>(outb, h1, w2f, b2f, rowp, esrc, eidx, aggr);
    k_node<<<256, 512, 0, stream>>>(outb, aggr, cntb, convW, convB, gWih, gWhh, gbih, gbhh);
  }

  for (int st = 0; st < 3; st++){
    k_s2s_lstm<<<1, 64, 0, stream>>>(sWih, sWhh, sbih, sbhh, scal, st == 0 ? 1 : 0);
    k_dots<<<cN / 256, 256, 0, stream>>>(outb, scal, sbuf);
    k_sm<<<cN / 256, 256, 0, stream>>>(outb, sbuf, scal);
  }

  k_memlstm<<<1, 64, 0, stream>>>(mWih, mWhh, mbih, mbhh, hx, cx, W_lin3, b_lin3, scal, dout);
  k_head<<<cT / 4, 256, 0, stream>>>(outb, nonring, scal, W_lin1, b_lin1, W_lin2, b_lin2, dout);
}

// Round 4
// 743.876 us; speedup vs baseline: 2.5374x; 1.3730x over previous
//
#include <hip/hip_runtime.h>

#define cN 16384
#define cE 65536
#define cT 2048
#define CAP 104
#define SST 1032   // S row stride (shorts): 2064B = 516 words == 4 (mod 32) -> conflict-free b128

typedef __attribute__((ext_vector_type(8))) short short8;
typedef __attribute__((ext_vector_type(4))) float f32x4;

__device__ __forceinline__ short f2bf(float f){
  unsigned u = __float_as_uint(f);
  u = (u + 0x7FFFu + ((u >> 16) & 1u)) >> 16;
  return (short)u;
}
__device__ __forceinline__ float bf2f(short s){
  return __uint_as_float(((unsigned)(unsigned short)s) << 16);
}
__device__ __forceinline__ float sigm(float x){ return 1.f / (1.f + __expf(-x)); }
__device__ __forceinline__ unsigned fenc(float f){
  unsigned u = __float_as_uint(f);
  return (u & 0x80000000u) ? ~u : (u | 0x80000000u);
}
__device__ __forceinline__ float fdec(unsigned u){
  u = (u & 0x80000000u) ? (u & 0x7FFFFFFFu) : ~u;
  return __uint_as_float(u);
}
__device__ __forceinline__ float wred(float v){
  v += __shfl_xor(v, 32); v += __shfl_xor(v, 16); v += __shfl_xor(v, 8);
  v += __shfl_xor(v, 4);  v += __shfl_xor(v, 2);  v += __shfl_xor(v, 1);
  return v;
}

// out = relu(x @ W_lin0.T + b)
__global__ __launch_bounds__(256) void k_lin0(const float* __restrict__ x,
    const float* __restrict__ W, const float* __restrict__ b, float* __restrict__ out)
{
  int i = blockIdx.x * 256 + threadIdx.x;       // cN*64
  int n = i >> 6, f = i & 63;
  float acc = b[f] + x[n*3]*W[f*3] + x[n*3+1]*W[f*3+1] + x[n*3+2]*W[f*3+2];
  out[i] = fmaxf(acc, 0.f);
}

// h1 = bf16(relu(edge_attr @ W_e1.T + b_e1))
__global__ __launch_bounds__(256) void k_h1(const float* __restrict__ ea,
    const float* __restrict__ W, const float* __restrict__ b, short* __restrict__ h1)
{
  int i = blockIdx.x * 256 + threadIdx.x;       // cE*128
  int e = i >> 7, k = i & 127;
  const float* a = ea + e * 7;
  const float* w = W + k * 7;
  float acc = b[k];
  #pragma unroll
  for (int c = 0; c < 7; c++) acc += a[c] * w[c];
  h1[i] = f2bf(fmaxf(acc, 0.f));
}

// W2 -> fragment-major bf16 layout for the S-contraction B operand.
__global__ __launch_bounds__(256) void k_w2f(const float* __restrict__ W2, short* __restrict__ w2f)
{
  int o = blockIdx.x * 256 + threadIdx.x;       // 524288
  int j = o & 7, l = (o >> 3) & 63, ks = (o >> 9) & 31, c = (o >> 14) & 7, fb = (o >> 17) & 3;
  int col = c * 1024 + ks * 32 + ((l >> 4) & 3) * 8 + j;
  int f = fb * 16 + (l & 15);
  int d = col >> 7, k = col & 127;
  w2f[o] = f2bf(W2[d * 8192 + f * 128 + k]);
}

// b2 -> B-fragment layout for the bias MFMA
__global__ __launch_bounds__(256) void k_b2f(const float* __restrict__ b2, short* __restrict__ b2f)
{
  int o = blockIdx.x * 256 + threadIdx.x;       // 4096
  int j = o & 7, l = (o >> 3) & 63, ks2 = (o >> 9) & 1, fb = (o >> 10) & 3;
  int d = ks2 * 32 + ((l >> 4) & 3) * 8 + j;
  int f = fb * 16 + (l & 15);
  b2f[o] = f2bf(b2[d * 64 + f]);
}

__global__ __launch_bounds__(256) void k_deg(const int* __restrict__ ei, int* __restrict__ deg)
{
  int e = blockIdx.x * 256 + threadIdx.x;
  atomicAdd(&deg[ei[cE + e]], 1);
}

// exclusive scan over 16384 degrees; also fills cnt = max(deg,1)
__global__ __launch_bounds__(1024) void k_scan(const int* __restrict__ deg,
    int* __restrict__ rowp, float* __restrict__ cnt)
{
  __shared__ int part[1024];
  int tid = threadIdx.x;
  int base = tid * 16;
  int loc[16]; int s = 0;
  #pragma unroll
  for (int i = 0; i < 16; i++){ loc[i] = s; s += deg[base + i]; }
  part[tid] = s;
  __syncthreads();
  for (int off = 1; off < 1024; off <<= 1){
    int v = (tid >= off) ? part[tid - off] : 0;
    __syncthreads();
    part[tid] += v;
    __syncthreads();
  }
  int inc = part[tid];
  int eb = inc - s;
  #pragma unroll
  for (int i = 0; i < 16; i++){
    rowp[base + i] = eb + loc[i];
    int dv = deg[base + i];
    cnt[base + i] = (float)(dv > 0 ? dv : 1);
  }
  if (tid == 1023) rowp[16384] = inc;
}

__global__ __launch_bounds__(256) void k_scatter(const int* __restrict__ ei,
    const int* __restrict__ rowp, int* __restrict__ cur,
    int* __restrict__ esrc, int* __restrict__ eidx)
{
  int e = blockIdx.x * 256 + threadIdx.x;
  int t = ei[cE + e];
  int pos = rowp[t] + atomicAdd(&cur[t], 1);
  esrc[pos] = ei[e];
  eidx[pos] = e;
}

// Fused bilinear aggregation with LDS-staged edge data.
__global__ __launch_bounds__(256) void k_sagg(const float* __restrict__ out,
    const short* __restrict__ h1, const short* __restrict__ w2f,
    const short* __restrict__ b2f, const int* __restrict__ rowp,
    const int* __restrict__ esrc, const int* __restrict__ eidx,
    float* __restrict__ aggr)
{
  __shared__ __align__(16) short S[16][SST];
  __shared__ __align__(16) short h1s[CAP][128];
  __shared__ __align__(16) short outs[CAP][64];
  __shared__ __align__(16) short osb[16][72];
  int tid = threadIdx.x, w = tid >> 6, lane = tid & 63;
  int t0 = blockIdx.x * 16;

  int ebase = rowp[t0];
  int eend  = rowp[t0 + 16];
  int ecnt  = eend - ebase;
  bool fits = (ecnt <= CAP);
  int scnt  = fits ? ecnt : CAP;
  // ---- stage edge data once (coalesced) ----
  for (int i = w; i < scnt; i += 4){
    int eid = eidx[ebase + i];
    int src = esrc[ebase + i];
    h1s[i][lane]      = h1[(size_t)eid * 128 + lane];
    h1s[i][64 + lane] = h1[(size_t)eid * 128 + 64 + lane];
    outs[i][lane]     = f2bf(out[(size_t)src * 64 + lane]);
  }
  // per-wave target slices
  int toff[4], tcnt[4];
  #pragma unroll
  for (int g = 0; g < 4; g++){
    int t = t0 + w * 4 + g;
    int a = rowp[t], b = rowp[t + 1];
    toff[g] = a - ebase; tcnt[g] = b - a;
  }
  __syncthreads();

  f32x4 acc = {0.f, 0.f, 0.f, 0.f};
  int arow = lane & 15, kg = lane >> 4;
  for (int c = 0; c < 8; ++c){
    // ---- phase A: build S-slice from LDS-staged data ----
    #pragma unroll
    for (int g = 0; g < 4; ++g){
      int ti = w * 4 + g;
      float a0[8], a1[8], osd[8];
      #pragma unroll
      for (int d = 0; d < 8; d++){ a0[d] = 0.f; a1[d] = 0.f; osd[d] = 0.f; }
      int tc = tcnt[g], tf = toff[g];
      if (fits){
        #pragma unroll 2
        for (int p = 0; p < tc; ++p){
          int slot = tf + p;
          float h1a = bf2f(h1s[slot][lane]);
          float h1b = bf2f(h1s[slot][64 + lane]);
          short8 ov = *(const short8*)&outs[slot][c * 8];
          #pragma unroll
          for (int d = 0; d < 8; d++){
            float o = bf2f(ov[d]);
            a0[d] += o * h1a; a1[d] += o * h1b; osd[d] += o;
          }
        }
      } else {
        for (int p = 0; p < tc; ++p){
          int slot = tf + p;
          if (slot < CAP){
            float h1a = bf2f(h1s[slot][lane]);
            float h1b = bf2f(h1s[slot][64 + lane]);
            short8 ov = *(const short8*)&outs[slot][c * 8];
            #pragma unroll
            for (int d = 0; d < 8; d++){
              float o = bf2f(ov[d]);
              a0[d] += o * h1a; a1[d] += o * h1b; osd[d] += o;
            }
          } else {
            int eid = eidx[ebase + slot];
            int src = esrc[ebase + slot];
            float h1a = bf2f(h1[(size_t)eid * 128 + lane]);
            float h1b = bf2f(h1[(size_t)eid * 128 + 64 + lane]);
            #pragma unroll
            for (int d = 0; d < 8; d++){
              float o = out[(size_t)src * 64 + c * 8 + d];
              a0[d] += o * h1a; a1[d] += o * h1b; osd[d] += o;
            }
          }
        }
      }
      #pragma unroll
      for (int d = 0; d < 8; d++){
        S[ti][d * 128 + lane]      = f2bf(a0[d]);
        S[ti][d * 128 + 64 + lane] = f2bf(a1[d]);
      }
      if (lane == 0){
        #pragma unroll
        for (int d = 0; d < 8; d++) osb[ti][c * 8 + d] = f2bf(osd[d]);
      }
    }
    __syncthreads();
    // ---- phase B: MFMA contraction for this chunk (K=1024) ----
    const short* bbase = w2f + ((size_t)(w * 8 + c) * 32) * 512 + lane * 8;
    #pragma unroll
    for (int ks = 0; ks < 32; ++ks){
      short8 afr = *(const short8*)&S[arow][kg * 8 + ks * 32];
      short8 bfr = *(const short8*)(bbase + (size_t)ks * 512);
      acc = __builtin_amdgcn_mfma_f32_16x16x32_bf16(afr, bfr, acc, 0, 0, 0);
    }
    __syncthreads();
  }
  // ---- bias term as 2 MFMA steps: acc += os @ B2 ----
  #pragma unroll
  for (int ks2 = 0; ks2 < 2; ++ks2){
    short8 osf = *(const short8*)&osb[arow][ks2 * 32 + kg * 8];
    short8 bfr = *(const short8*)(b2f + ((size_t)((w * 2 + ks2) * 64 + lane)) * 8);
    acc = __builtin_amdgcn_mfma_f32_16x16x32_bf16(osf, bfr, acc, 0, 0, 0);
  }
  // ---- store raw sums ----
  int fcol = w * 16 + arow;
  int trow = kg * 4;
  #pragma unroll
  for (int q = 0; q < 4; q++)
    aggr[(size_t)(t0 + trow + q) * 64 + fcol] = acc[q];
}

// node update: m = relu(aggr/cnt + out@conv + cb); GRU(m, out) -> out (in place)
__global__ __launch_bounds__(512) void k_node(float* __restrict__ out,
    const float* __restrict__ aggr, const float* __restrict__ cnt,
    const float* __restrict__ convW, const float* __restrict__ convB,
    const float* __restrict__ Wih, const float* __restrict__ Whh,
    const float* __restrict__ bih, const float* __restrict__ bhh)
{
  __shared__ float sconv[64 * 64];      // [d][f]
  __shared__ float sih[64 * 192];       // [d][gf] (transposed)
  __shared__ float shh[64 * 192];
  __shared__ float sbias[64 + 192 + 192];
  __shared__ float so[8][64], sm[8][64];
  int tid = threadIdx.x;
  for (int i = tid; i < 4096; i += 512) sconv[i] = convW[i];
  for (int i = tid; i < 12288; i += 512){
    int d = i / 192, gf = i % 192;
    sih[i] = Wih[gf * 64 + d];
    shh[i] = Whh[gf * 64 + d];
  }
  if (tid < 64) sbias[tid] = convB[tid];
  for (int i = tid; i < 192; i += 512){ sbias[64 + i] = bih[i]; sbias[256 + i] = bhh[i]; }
  __syncthreads();
  int wid = tid >> 6, lane = tid & 63;
  int gw = blockIdx.x * 8 + wid;        // 2048 waves total
  for (int it = 0; it < 8; it++){
    int n = it * 2048 + gw;
    float o = out[n * 64 + lane];
    so[wid][lane] = o;
    __syncthreads();
    float ic = 1.0f / fmaxf(cnt[n], 1.0f);
    float acc = aggr[n * 64 + lane] * ic + sbias[lane];
    #pragma unroll 8
    for (int d = 0; d < 64; d++) acc += so[wid][d] * sconv[d * 64 + lane];
    float m = fmaxf(acc, 0.f);
    sm[wid][lane] = m;
    __syncthreads();
    float gr = sbias[64 + lane], gz = sbias[128 + lane], gn = sbias[192 + lane];
    float hr = sbias[256 + lane], hz = sbias[320 + lane], hn = sbias[384 + lane];
    #pragma unroll 4
    for (int d = 0; d < 64; d++){
      float md = sm[wid][d], od = so[wid][d];
      const float* wi = &sih[d * 192];
      const float* wh = &shh[d * 192];
      gr += md * wi[lane];       gz += md * wi[64 + lane];  gn += md * wi[128 + lane];
      hr += od * wh[lane];       hz += od * wh[64 + lane];  hn += od * wh[128 + lane];
    }
    float r = sigm(gr + hr);
    float z = sigm(gz + hz);
    float nn = tanhf(gn + r * hn);
    out[n * 64 + lane] = (1.f - z) * nn + z * o;
    __syncthreads();
  }
}

// Set2Set LSTM step, wave-parallel: wave g computes gate g (64 outputs, lanes over j).
__global__ __launch_bounds__(256) void k_s2s_lstm(const float* __restrict__ Wih,
    const float* __restrict__ Whh, const float* __restrict__ bih,
    const float* __restrict__ bhh, float* __restrict__ scal, int first)
{
  __shared__ float q[128];
  __shared__ float hsL[64];
  __shared__ float gsh[4][64];
  int tid = threadIdx.x, gg = tid >> 6, lane = tid & 63;
  if (gg == 0){
    float hs = first ? 0.f : scal[lane];
    float rv = first ? 0.f : scal[128 + lane] / scal[193];
    q[lane] = hs; q[64 + lane] = rv; hsL[lane] = hs;
  }
  __syncthreads();
  float2 fq = *(const float2*)&q[2 * lane];
  float hv = hsL[lane];
  #pragma unroll 4
  for (int o = 0; o < 64; o++){
    int row = gg * 64 + o;
    float2 wv = *(const float2*)&Wih[(size_t)row * 128 + 2 * lane];
    float s = wv.x * fq.x + wv.y * fq.y + Whh[(size_t)row * 64 + lane] * hv;
    s = wred(s);
    if (lane == 0) gsh[gg][o] = s;
  }
  __syncthreads();
  if (gg == 0){
    float gi = gsh[0][lane] + bih[lane]       + bhh[lane];
    float gf = gsh[1][lane] + bih[64 + lane]  + bhh[64 + lane];
    float gv = gsh[2][lane] + bih[128 + lane] + bhh[128 + lane];
    float go = gsh[3][lane] + bih[192 + lane] + bhh[192 + lane];
    float cs = first ? 0.f : scal[64 + lane];
    float cn = sigm(gf) * cs + sigm(gi) * tanhf(gv);
    float hn = sigm(go) * tanhf(cn);
    scal[lane] = hn; scal[64 + lane] = cn; scal[128 + lane] = 0.f;
    if (lane == 0){ ((unsigned*)scal)[192] = 0u; scal[193] = 0.f; }
  }
}

// s[n] = out[n,:].hs ; global max via encoded atomicMax.  64 nodes/block.
__global__ __launch_bounds__(256) void k_dots(const float* __restrict__ out,
    float* __restrict__ scal, float* __restrict__ sbuf)
{
  __shared__ float hsh[64];
  __shared__ float smax[4];
  int tid = threadIdx.x, wid = tid >> 6, lane = tid & 63;
  if (tid < 64) hsh[tid] = scal[tid];
  __syncthreads();
  int nbase = blockIdx.x * 64 + wid * 16;
  float hv = hsh[lane];
  float wmax = -3.4e38f;
  #pragma unroll 4
  for (int i = 0; i < 16; i++){
    int n = nbase + i;
    float p = wred(out[(size_t)n * 64 + lane] * hv);
    if (lane == 0) sbuf[n] = p;
    wmax = fmaxf(wmax, p);
  }
  if (lane == 0) smax[wid] = wmax;
  __syncthreads();
  if (tid == 0){
    float m = fmaxf(fmaxf(smax[0], smax[1]), fmaxf(smax[2], smax[3]));
    atomicMax((unsigned*)(scal + 192), fenc(m));
  }
}

// e = exp(s - gmax); accumulate esum and r_raw.  64 nodes/block.
__global__ __launch_bounds__(256) void k_sm(const float* __restrict__ out,
    const float* __restrict__ sbuf, float* __restrict__ scal)
{
  __shared__ float ebuf[64];
  __shared__ float rpart[4][64];
  int tid = threadIdx.x, wid = tid >> 6, lane = tid & 63;
  float gm = fdec(((const unsigned*)scal)[192]);
  int n0 = blockIdx.x * 64;
  if (tid < 64) ebuf[tid] = __expf(sbuf[n0 + tid] - gm);
  __syncthreads();
  float racc = 0.f;
  #pragma unroll 4
  for (int i = 0; i < 16; i++){
    int idx = wid * 16 + i;
    racc += ebuf[idx] * out[(size_t)(n0 + idx) * 64 + lane];
  }
  rpart[wid][lane] = racc;
  __syncthreads();
  if (wid == 0){
    float rt = rpart[0][lane] + rpart[1][lane] + rpart[2][lane] + rpart[3][lane];
    atomicAdd(&scal[128 + lane], rt);
  } else if (wid == 1){
    float es = wred(ebuf[lane]);
    if (lane == 0) atomicAdd(&scal[193], es);
  }
}

// memory LSTM + value head, wave-parallel gates.
__global__ __launch_bounds__(256) void k_memlstm(const float* __restrict__ Wih,
    const float* __restrict__ Whh, const float* __restrict__ bih,
    const float* __restrict__ bhh, const float* __restrict__ hx,
    const float* __restrict__ cx, const float* __restrict__ W3,
    const float* __restrict__ b3, float* __restrict__ scal, float* __restrict__ dout)
{
  __shared__ float pool[128];
  __shared__ float hxs[64];
  __shared__ float gsh[4][64];
  __shared__ float lob[64];
  int tid = threadIdx.x, gg = tid >> 6, lane = tid & 63;
  if (gg == 0){
    pool[lane] = scal[lane];
    pool[64 + lane] = scal[128 + lane] / scal[193];
    hxs[lane] = hx[lane];
  }
  __syncthreads();
  float2 fq = *(const float2*)&pool[2 * lane];
  float hv = hxs[lane];
  #pragma unroll 4
  for (int o = 0; o < 64; o++){
    int row = gg * 64 + o;
    float2 wv = *(const float2*)&Wih[(size_t)row * 128 + 2 * lane];
    float s = wv.x * fq.x + wv.y * fq.y + Whh[(size_t)row * 64 + lane] * hv;
    s = wred(s);
    if (lane == 0) gsh[gg][o] = s;
  }
  __syncthreads();
  if (gg == 0){
    float gi = gsh[0][lane] + bih[lane]       + bhh[lane];
    float gf = gsh[1][lane] + bih[64 + lane]  + bhh[64 + lane];
    float gv = gsh[2][lane] + bih[128 + lane] + bhh[128 + lane];
    float go = gsh[3][lane] + bih[192 + lane] + bhh[192 + lane];
    float cn = sigm(gf) * cx[lane] + sigm(gi) * tanhf(gv);
    float hn = sigm(go) * tanhf(cn);
    dout[12289 + lane] = hn;     // hx_new
    dout[12353 + lane] = cn;     // cx_new
    scal[256 + lane] = hn;       // lstm_out for head
    lob[lane] = hn;
  }
  __syncthreads();
  if (gg == 0){
    float a = pool[lane] * W3[lane] + pool[64 + lane] * W3[64 + lane]
            + lob[lane] * W3[128 + lane];
    a = wred(a);
    if (lane == 0) dout[12288] = a + b3[0];
  }
}

// torsion head. pf[t, j<256] = out[nr[j*32 + t/64], t%64]; pf[t, 256..319] = lstm_out[t>>5]
__global__ __launch_bounds__(256) void k_head(const float* __restrict__ out,
    const int* __restrict__ nr, const float* __restrict__ scal,
    const float* __restrict__ W1, const float* __restrict__ b1,
    const float* __restrict__ W2, const float* __restrict__ b2,
    float* __restrict__ dout)
{
  __shared__ float pf[4][320];
  __shared__ float hb[4][64];
  int tid = threadIdx.x, wid = tid >> 6, lane = tid & 63;
  int t = blockIdx.x * 4 + wid;
  float lo = scal[256 + (t >> 5)];
  #pragma unroll
  for (int rep = 0; rep < 4; rep++){
    int j = rep * 64 + lane;
    int idx = nr[j * 32 + (t >> 6)];
    pf[wid][j] = out[idx * 64 + (t & 63)];
  }
  pf[wid][256 + lane] = lo;
  __syncthreads();
  float acc = b1[lane];
  const float* w = W1 + lane * 320;
  #pragma unroll 4
  for (int j = 0; j < 320; j++) acc += pf[wid][j] * w[j];
  hb[wid][lane] = fmaxf(acc, 0.f);
  __syncthreads();
  if (lane < 6){
    float a2 = b2[lane];
    const float* w2 = W2 + lane * 64;
    #pragma unroll 4
    for (int f = 0; f < 64; f++) a2 += hb[wid][f] * w2[f];
    dout[t * 6 + lane] = a2;
  }
}

extern "C" void kernel_launch(void* const* d_in, const int* in_sizes, int n_in,
                              void* d_out, int out_size, void* d_ws, size_t ws_size,
                              hipStream_t stream)
{
  const float* x         = (const float*)d_in[0];
  const float* edge_attr = (const float*)d_in[1];
  const int*   ei        = (const int*)d_in[2];
  const int*   nonring   = (const int*)d_in[3];
  const float* hx        = (const float*)d_in[4];
  const float* cx        = (const float*)d_in[5];
  const float* W_lin0 = (const float*)d_in[6];  const float* b_lin0 = (const float*)d_in[7];
  const float* W_e1   = (const float*)d_in[8];  const float* b_e1   = (const float*)d_in[9];
  const float* W_e2   = (const float*)d_in[10]; const float* b_e2   = (const float*)d_in[11];
  const float* convW  = (const float*)d_in[12]; const float* convB  = (const float*)d_in[13];
  const float* gWih   = (const float*)d_in[14]; const float* gWhh   = (const float*)d_in[15];
  const float* gbih   = (const float*)d_in[16]; const float* gbhh   = (const float*)d_in[17];
  const float* sWih   = (const float*)d_in[18]; const float* sWhh   = (const float*)d_in[19];
  const float* sbih   = (const float*)d_in[20]; const float* sbhh   = (const float*)d_in[21];
  const float* mWih   = (const float*)d_in[22]; const float* mWhh   = (const float*)d_in[23];
  const float* mbih   = (const float*)d_in[24]; const float* mbhh   = (const float*)d_in[25];
  const float* W_lin1 = (const float*)d_in[26]; const float* b_lin1 = (const float*)d_in[27];
  const float* W_lin2 = (const float*)d_in[28]; const float* b_lin2 = (const float*)d_in[29];
  const float* W_lin3 = (const float*)d_in[30]; const float* b_lin3 = (const float*)d_in[31];
  float* dout = (float*)d_out;

  char* w = (char*)d_ws;
  float* outb = (float*)w;  w += (size_t)cN * 64 * 4;
  float* aggr = (float*)w;  w += (size_t)cN * 64 * 4;
  short* h1   = (short*)w;  w += (size_t)cE * 128 * 2;
  short* w2f  = (short*)w;  w += (size_t)64 * 8192 * 2;
  short* b2f  = (short*)w;  w += 4096 * 2;
  float* cntb = (float*)w;  w += cN * 4;
  float* sbuf = (float*)w;  w += cN * 4;
  float* scal = (float*)w;  w += 512 * 4;
  int* deg  = (int*)w;  w += cN * 4;
  int* cur  = (int*)w;  w += cN * 4;
  int* rowp = (int*)w;  w += (cN + 1) * 4 + 60;   // keep alignment
  int* esrc = (int*)w;  w += cE * 4;
  int* eidx = (int*)w;  w += cE * 4;

  hipMemsetAsync(deg, 0, cN * 4, stream);
  hipMemsetAsync(cur, 0, cN * 4, stream);

  k_lin0<<<cN * 64 / 256, 256, 0, stream>>>(x, W_lin0, b_lin0, outb);
  k_h1<<<cE * 128 / 256, 256, 0, stream>>>(edge_attr, W_e1, b_e1, h1);
  k_w2f<<<64 * 8192 / 256, 256, 0, stream>>>(W_e2, w2f);
  k_b2f<<<16, 256, 0, stream>>>(b_e2, b2f);
  k_deg<<<cE / 256, 256, 0, stream>>>(ei, deg);
  k_scan<<<1, 1024, 0, stream>>>(deg, rowp, cntb);
  k_scatter<<<cE / 256, 256, 0, stream>>>(ei, rowp, cur, esrc, eidx);

  for (int it = 0; it < 3; it++){
    k_sagg<<<cN / 16, 256, 0, stream>>>(outb, h1, w2f, b2f, rowp, esrc, eidx, aggr);
    k_node<<<256, 512, 0, stream>>>(outb, aggr, cntb, convW, convB, gWih, gWhh, gbih, gbhh);
  }

  for (int st = 0; st < 3; st++){
    k_s2s_lstm<<<1, 256, 0, stream>>>(sWih, sWhh, sbih, sbhh, scal, st == 0 ? 1 : 0);
    k_dots<<<cN / 64, 256, 0, stream>>>(outb, scal, sbuf);
    k_sm<<<cN / 64, 256, 0, stream>>>(outb, sbuf, scal);
  }

  k_memlstm<<<1, 256, 0, stream>>>(mWih, mWhh, mbih, mbhh, hx, cx, W_lin3, b_lin3, scal, dout);
  k_head<<<cT / 4, 256, 0, stream>>>(outb, nonring, scal, W_lin1, b_lin1, W_lin2, b_lin2, dout);
}

// Round 5
// 672.380 us; speedup vs baseline: 2.8072x; 1.1063x over previous
//
#include <hip/hip_runtime.h>

#define cN 16384
#define cE 65536
#define cT 2048
#define CAP 88

typedef __attribute__((ext_vector_type(8))) short short8;
typedef __attribute__((ext_vector_type(4))) float f32x4;
typedef __attribute__((ext_vector_type(4))) unsigned u32x4;

__device__ __forceinline__ short f2bf(float f){
  unsigned u = __float_as_uint(f);
  u = (u + 0x7FFFu + ((u >> 16) & 1u)) >> 16;
  return (short)u;
}
__device__ __forceinline__ float bf2f(short s){
  return __uint_as_float(((unsigned)(unsigned short)s) << 16);
}
__device__ __forceinline__ unsigned cvtpk(float lo, float hi){
  unsigned r;
  asm("v_cvt_pk_bf16_f32 %0, %1, %2" : "=v"(r) : "v"(lo), "v"(hi));
  return r;
}
__device__ __forceinline__ float sigm(float x){ return 1.f / (1.f + __expf(-x)); }
__device__ __forceinline__ unsigned fenc(float f){
  unsigned u = __float_as_uint(f);
  return (u & 0x80000000u) ? ~u : (u | 0x80000000u);
}
__device__ __forceinline__ float fdec(unsigned u){
  u = (u & 0x80000000u) ? (u & 0x7FFFFFFFu) : ~u;
  return __uint_as_float(u);
}
__device__ __forceinline__ float wred(float v){
  v += __shfl_xor(v, 32); v += __shfl_xor(v, 16); v += __shfl_xor(v, 8);
  v += __shfl_xor(v, 4);  v += __shfl_xor(v, 2);  v += __shfl_xor(v, 1);
  return v;
}

// out = relu(x @ W_lin0.T + b)
__global__ __launch_bounds__(256) void k_lin0(const float* __restrict__ x,
    const float* __restrict__ W, const float* __restrict__ b, float* __restrict__ out)
{
  int i = blockIdx.x * 256 + threadIdx.x;       // cN*64
  int n = i >> 6, f = i & 63;
  float acc = b[f] + x[n*3]*W[f*3] + x[n*3+1]*W[f*3+1] + x[n*3+2]*W[f*3+2];
  out[i] = fmaxf(acc, 0.f);
}

// h1 = bf16(relu(edge_attr @ W_e1.T + b_e1))
__global__ __launch_bounds__(256) void k_h1(const float* __restrict__ ea,
    const float* __restrict__ W, const float* __restrict__ b, short* __restrict__ h1)
{
  int i = blockIdx.x * 256 + threadIdx.x;       // cE*128
  int e = i >> 7, k = i & 127;
  const float* a = ea + e * 7;
  const float* w = W + k * 7;
  float acc = b[k];
  #pragma unroll
  for (int c = 0; c < 7; c++) acc += a[c] * w[c];
  h1[i] = f2bf(fmaxf(acc, 0.f));
}

// W2 -> fragment-major bf16 layout, chunk-local k-major element order:
// col-in-chunk pos = ks*32 + kg*8 + j  <->  (k = ks*4 + kg, d = c*8 + j)
__global__ __launch_bounds__(256) void k_w2f(const float* __restrict__ W2, short* __restrict__ w2f)
{
  int o = blockIdx.x * 256 + threadIdx.x;       // 524288
  int j = o & 7, l = (o >> 3) & 63, ks = (o >> 9) & 31, c = (o >> 14) & 7, fb = (o >> 17) & 3;
  int f = fb * 16 + (l & 15);
  int d = c * 8 + j;
  int k = ks * 4 + ((l >> 4) & 3);
  w2f[o] = f2bf(W2[(d * 64 + f) * 128 + k]);
}

// b2 -> B-fragment layout for the bias MFMA (d = ks2*32 + kg*8 + j)
__global__ __launch_bounds__(256) void k_b2f(const float* __restrict__ b2, short* __restrict__ b2f)
{
  int o = blockIdx.x * 256 + threadIdx.x;       // 4096
  int j = o & 7, l = (o >> 3) & 63, ks2 = (o >> 9) & 1, fb = (o >> 10) & 3;
  int d = ks2 * 32 + ((l >> 4) & 3) * 8 + j;
  int f = fb * 16 + (l & 15);
  b2f[o] = f2bf(b2[d * 64 + f]);
}

__global__ __launch_bounds__(256) void k_deg(const int* __restrict__ ei, int* __restrict__ deg)
{
  int e = blockIdx.x * 256 + threadIdx.x;
  atomicAdd(&deg[ei[cE + e]], 1);
}

// exclusive scan over 16384 degrees; also fills cnt = max(deg,1)
__global__ __launch_bounds__(1024) void k_scan(const int* __restrict__ deg,
    int* __restrict__ rowp, float* __restrict__ cnt)
{
  __shared__ int part[1024];
  int tid = threadIdx.x;
  int base = tid * 16;
  int loc[16]; int s = 0;
  #pragma unroll
  for (int i = 0; i < 16; i++){ loc[i] = s; s += deg[base + i]; }
  part[tid] = s;
  __syncthreads();
  for (int off = 1; off < 1024; off <<= 1){
    int v = (tid >= off) ? part[tid - off] : 0;
    __syncthreads();
    part[tid] += v;
    __syncthreads();
  }
  int inc = part[tid];
  int eb = inc - s;
  #pragma unroll
  for (int i = 0; i < 16; i++){
    rowp[base + i] = eb + loc[i];
    int dv = deg[base + i];
    cnt[base + i] = (float)(dv > 0 ? dv : 1);
  }
  if (tid == 1023) rowp[16384] = inc;
}

__global__ __launch_bounds__(256) void k_scatter(const int* __restrict__ ei,
    const int* __restrict__ rowp, int* __restrict__ cur,
    int* __restrict__ esrc, int* __restrict__ eidx)
{
  int e = blockIdx.x * 256 + threadIdx.x;
  int t = ei[cE + e];
  int pos = rowp[t] + atomicAdd(&cur[t], 1);
  esrc[pos] = ei[e];
  eidx[pos] = e;
}

// Fused bilinear aggregation.
// aggr[t,f] = sum_{d,k} S_t[d,k]*W2[(d,f),k] + sum_d os_t[d]*b2[d*64+f]  (raw; /cnt in k_node)
__global__ __launch_bounds__(256) void k_sagg(const float* __restrict__ out,
    const short* __restrict__ h1, const short* __restrict__ w2f,
    const short* __restrict__ b2f, const int* __restrict__ rowp,
    const int* __restrict__ esrc, const int* __restrict__ eidx,
    float* __restrict__ aggr)
{
  __shared__ __align__(16) short S[16][1040];       // chunk-local pos = k*8 + d
  __shared__ __align__(16) unsigned h1i[CAP][64];   // packed (h1[k=lane], h1[k=64+lane])
  __shared__ __align__(16) float outsf[CAP][64];
  __shared__ __align__(16) short osb[16][72];
  int tid = threadIdx.x, w = tid >> 6, lane = tid & 63;
  int t0 = blockIdx.x * 16;

  int ebase = rowp[t0];
  int eend  = rowp[t0 + 16];
  int ecnt  = eend - ebase;
  bool fits = (ecnt <= CAP);
  int scnt  = fits ? ecnt : CAP;
  // ---- stage edge data once (coalesced) ----
  for (int i = w; i < scnt; i += 4){
    int eid = eidx[ebase + i];
    int src = esrc[ebase + i];
    unsigned lo = (unsigned short)h1[(size_t)eid * 128 + lane];
    unsigned hi = (unsigned short)h1[(size_t)eid * 128 + 64 + lane];
    h1i[i][lane] = lo | (hi << 16);
    outsf[i][lane] = out[(size_t)src * 64 + lane];
  }
  // per-wave target slices
  int toff[4], tcnt[4];
  #pragma unroll
  for (int g = 0; g < 4; g++){
    int t = t0 + w * 4 + g;
    int a = rowp[t], b = rowp[t + 1];
    toff[g] = a - ebase; tcnt[g] = b - a;
  }
  __syncthreads();

  // ---- os_t[d] once (lane = d), bf16 into osb ----
  #pragma unroll
  for (int g = 0; g < 4; g++){
    int ti = w * 4 + g;
    float os = 0.f;
    int tf = toff[g], tc = tcnt[g];
    for (int p = 0; p < tc; p++){
      int slot = tf + p;
      if (slot < CAP) os += outsf[slot][lane];
      else            os += out[(size_t)esrc[ebase + slot] * 64 + lane];
    }
    osb[ti][lane] = (short)cvtpk(os, os);
  }

  f32x4 acc = {0.f, 0.f, 0.f, 0.f};
  int arow = lane & 15, kg = lane >> 4;
  for (int c = 0; c < 8; ++c){
    // ---- phase A: accumulate S-slice (d = c*8 .. c*8+7; k = lane / 64+lane) ----
    #pragma unroll
    for (int g = 0; g < 4; ++g){
      int ti = w * 4 + g;
      float a0[8], a1[8];
      #pragma unroll
      for (int d = 0; d < 8; d++){ a0[d] = 0.f; a1[d] = 0.f; }
      int tc = tcnt[g], tf = toff[g];
      if (fits){
        #pragma unroll 2
        for (int p = 0; p < tc; ++p){
          int slot = tf + p;
          unsigned u = h1i[slot][lane];
          float h1a = __uint_as_float(u << 16);
          float h1b = __uint_as_float(u & 0xFFFF0000u);
          f32x4 o0 = *(const f32x4*)&outsf[slot][c * 8];
          f32x4 o1 = *(const f32x4*)&outsf[slot][c * 8 + 4];
          a0[0] = fmaf(o0[0], h1a, a0[0]); a1[0] = fmaf(o0[0], h1b, a1[0]);
          a0[1] = fmaf(o0[1], h1a, a0[1]); a1[1] = fmaf(o0[1], h1b, a1[1]);
          a0[2] = fmaf(o0[2], h1a, a0[2]); a1[2] = fmaf(o0[2], h1b, a1[2]);
          a0[3] = fmaf(o0[3], h1a, a0[3]); a1[3] = fmaf(o0[3], h1b, a1[3]);
          a0[4] = fmaf(o1[0], h1a, a0[4]); a1[4] = fmaf(o1[0], h1b, a1[4]);
          a0[5] = fmaf(o1[1], h1a, a0[5]); a1[5] = fmaf(o1[1], h1b, a1[5]);
          a0[6] = fmaf(o1[2], h1a, a0[6]); a1[6] = fmaf(o1[2], h1b, a1[6]);
          a0[7] = fmaf(o1[3], h1a, a0[7]); a1[7] = fmaf(o1[3], h1b, a1[7]);
        }
      } else {
        for (int p = 0; p < tc; ++p){
          int slot = tf + p;
          float h1a, h1b;
          if (slot < CAP){
            unsigned u = h1i[slot][lane];
            h1a = __uint_as_float(u << 16);
            h1b = __uint_as_float(u & 0xFFFF0000u);
            f32x4 o0 = *(const f32x4*)&outsf[slot][c * 8];
            f32x4 o1 = *(const f32x4*)&outsf[slot][c * 8 + 4];
            #pragma unroll
            for (int d = 0; d < 4; d++){
              a0[d] = fmaf(o0[d], h1a, a0[d]); a1[d] = fmaf(o0[d], h1b, a1[d]);
              a0[4+d] = fmaf(o1[d], h1a, a0[4+d]); a1[4+d] = fmaf(o1[d], h1b, a1[4+d]);
            }
          } else {
            int eid = eidx[ebase + slot];
            int src = esrc[ebase + slot];
            h1a = bf2f(h1[(size_t)eid * 128 + lane]);
            h1b = bf2f(h1[(size_t)eid * 128 + 64 + lane]);
            #pragma unroll
            for (int d = 0; d < 8; d++){
              float o = out[(size_t)src * 64 + c * 8 + d];
              a0[d] = fmaf(o, h1a, a0[d]); a1[d] = fmaf(o, h1b, a1[d]);
            }
          }
        }
      }
      // S writes: k-major pos = k*8+d; one b128 per k (k=lane and k=64+lane)
      u32x4 p0, p1;
      p0[0] = cvtpk(a0[0], a0[1]); p0[1] = cvtpk(a0[2], a0[3]);
      p0[2] = cvtpk(a0[4], a0[5]); p0[3] = cvtpk(a0[6], a0[7]);
      p1[0] = cvtpk(a1[0], a1[1]); p1[1] = cvtpk(a1[2], a1[3]);
      p1[2] = cvtpk(a1[4], a1[5]); p1[3] = cvtpk(a1[6], a1[7]);
      *(u32x4*)&S[ti][lane * 8]       = p0;
      *(u32x4*)&S[ti][512 + lane * 8] = p1;
    }
    __syncthreads();
    // ---- phase B: MFMA contraction for this chunk (1024 elements) ----
    const short* bbase = w2f + ((size_t)(w * 8 + c) * 32) * 512 + lane * 8;
    #pragma unroll
    for (int ks = 0; ks < 32; ++ks){
      short8 afr = *(const short8*)&S[arow][ks * 32 + kg * 8];
      short8 bfr = *(const short8*)(bbase + (size_t)ks * 512);
      acc = __builtin_amdgcn_mfma_f32_16x16x32_bf16(afr, bfr, acc, 0, 0, 0);
    }
    __syncthreads();
  }
  // ---- bias term as 2 MFMA steps: acc += os @ B2 ----
  #pragma unroll
  for (int ks2 = 0; ks2 < 2; ++ks2){
    short8 osf = *(const short8*)&osb[arow][ks2 * 32 + kg * 8];
    short8 bfr = *(const short8*)(b2f + ((size_t)((w * 2 + ks2) * 64 + lane)) * 8);
    acc = __builtin_amdgcn_mfma_f32_16x16x32_bf16(osf, bfr, acc, 0, 0, 0);
  }
  // ---- store raw sums ----
  int fcol = w * 16 + arow;
  int trow = kg * 4;
  #pragma unroll
  for (int q = 0; q < 4; q++)
    aggr[(size_t)(t0 + trow + q) * 64 + fcol] = acc[q];
}

// node update: m = relu(aggr/cnt + out@conv + cb); GRU(m, out) -> out (in place)
// so/sm rows are wave-private -> no in-loop barriers needed.
__global__ __launch_bounds__(512) void k_node(float* __restrict__ out,
    const float* __restrict__ aggr, const float* __restrict__ cnt,
    const float* __restrict__ convW, const float* __restrict__ convB,
    const float* __restrict__ Wih, const float* __restrict__ Whh,
    const float* __restrict__ bih, const float* __restrict__ bhh)
{
  __shared__ float sconv[64 * 64];      // [d][f]
  __shared__ float sih[64 * 192];       // [d][gf] (transposed)
  __shared__ float shh[64 * 192];
  __shared__ float sbias[64 + 192 + 192];
  __shared__ float so[8][64], sm[8][64];
  int tid = threadIdx.x;
  for (int i = tid; i < 4096; i += 512) sconv[i] = convW[i];
  for (int i = tid; i < 12288; i += 512){
    int d = i / 192, gf = i % 192;
    sih[i] = Wih[gf * 64 + d];
    shh[i] = Whh[gf * 64 + d];
  }
  if (tid < 64) sbias[tid] = convB[tid];
  for (int i = tid; i < 192; i += 512){ sbias[64 + i] = bih[i]; sbias[256 + i] = bhh[i]; }
  __syncthreads();
  int wid = tid >> 6, lane = tid & 63;
  int gw = blockIdx.x * 8 + wid;        // 2048 waves total
  for (int it = 0; it < 8; it++){
    int n = it * 2048 + gw;
    float o = out[n * 64 + lane];
    so[wid][lane] = o;
    float ic = 1.0f / fmaxf(cnt[n], 1.0f);
    float acc = aggr[n * 64 + lane] * ic + sbias[lane];
    #pragma unroll 8
    for (int d = 0; d < 64; d++) acc += so[wid][d] * sconv[d * 64 + lane];
    float m = fmaxf(acc, 0.f);
    sm[wid][lane] = m;
    float gr = sbias[64 + lane], gz = sbias[128 + lane], gn = sbias[192 + lane];
    float hr = sbias[256 + lane], hz = sbias[320 + lane], hn = sbias[384 + lane];
    #pragma unroll 4
    for (int d = 0; d < 64; d++){
      float md = sm[wid][d], od = so[wid][d];
      const float* wi = &sih[d * 192];
      const float* wh = &shh[d * 192];
      gr += md * wi[lane];       gz += md * wi[64 + lane];  gn += md * wi[128 + lane];
      hr += od * wh[lane];       hz += od * wh[64 + lane];  hn += od * wh[128 + lane];
    }
    float r = sigm(gr + hr);
    float z = sigm(gz + hz);
    float nn = tanhf(gn + r * hn);
    out[n * 64 + lane] = (1.f - z) * nn + z * o;
  }
}

// Set2Set LSTM step, wave-parallel: wave g computes gate g (64 outputs, lanes over j).
__global__ __launch_bounds__(256) void k_s2s_lstm(const float* __restrict__ Wih,
    const float* __restrict__ Whh, const float* __restrict__ bih,
    const float* __restrict__ bhh, float* __restrict__ scal, int first)
{
  __shared__ float q[128];
  __shared__ float hsL[64];
  __shared__ float gsh[4][64];
  int tid = threadIdx.x, gg = tid >> 6, lane = tid & 63;
  if (gg == 0){
    float hs = first ? 0.f : scal[lane];
    float rv = first ? 0.f : scal[128 + lane] / scal[193];
    q[lane] = hs; q[64 + lane] = rv; hsL[lane] = hs;
  }
  __syncthreads();
  float2 fq = *(const float2*)&q[2 * lane];
  float hv = hsL[lane];
  #pragma unroll 4
  for (int o = 0; o < 64; o++){
    int row = gg * 64 + o;
    float2 wv = *(const float2*)&Wih[(size_t)row * 128 + 2 * lane];
    float s = wv.x * fq.x + wv.y * fq.y + Whh[(size_t)row * 64 + lane] * hv;
    s = wred(s);
    if (lane == 0) gsh[gg][o] = s;
  }
  __syncthreads();
  if (gg == 0){
    float gi = gsh[0][lane] + bih[lane]       + bhh[lane];
    float gf = gsh[1][lane] + bih[64 + lane]  + bhh[64 + lane];
    float gv = gsh[2][lane] + bih[128 + lane] + bhh[128 + lane];
    float go = gsh[3][lane] + bih[192 + lane] + bhh[192 + lane];
    float cs = first ? 0.f : scal[64 + lane];
    float cn = sigm(gf) * cs + sigm(gi) * tanhf(gv);
    float hn = sigm(go) * tanhf(cn);
    scal[lane] = hn; scal[64 + lane] = cn; scal[128 + lane] = 0.f;
    if (lane == 0){ ((unsigned*)scal)[192] = 0u; scal[193] = 0.f; }
  }
}

// s[n] = out[n,:].hs ; global max via encoded atomicMax.  64 nodes/block.
__global__ __launch_bounds__(256) void k_dots(const float* __restrict__ out,
    float* __restrict__ scal, float* __restrict__ sbuf)
{
  __shared__ float hsh[64];
  __shared__ float smax[4];
  int tid = threadIdx.x, wid = tid >> 6, lane = tid & 63;
  if (tid < 64) hsh[tid] = scal[tid];
  __syncthreads();
  int nbase = blockIdx.x * 64 + wid * 16;
  float hv = hsh[lane];
  float wmax = -3.4e38f;
  #pragma unroll 4
  for (int i = 0; i < 16; i++){
    int n = nbase + i;
    float p = wred(out[(size_t)n * 64 + lane] * hv);
    if (lane == 0) sbuf[n] = p;
    wmax = fmaxf(wmax, p);
  }
  if (lane == 0) smax[wid] = wmax;
  __syncthreads();
  if (tid == 0){
    float m = fmaxf(fmaxf(smax[0], smax[1]), fmaxf(smax[2], smax[3]));
    atomicMax((unsigned*)(scal + 192), fenc(m));
  }
}

// e = exp(s - gmax); accumulate esum and r_raw.  64 nodes/block.
__global__ __launch_bounds__(256) void k_sm(const float* __restrict__ out,
    const float* __restrict__ sbuf, float* __restrict__ scal)
{
  __shared__ float ebuf[64];
  __shared__ float rpart[4][64];
  int tid = threadIdx.x, wid = tid >> 6, lane = tid & 63;
  float gm = fdec(((const unsigned*)scal)[192]);
  int n0 = blockIdx.x * 64;
  if (tid < 64) ebuf[tid] = __expf(sbuf[n0 + tid] - gm);
  __syncthreads();
  float racc = 0.f;
  #pragma unroll 4
  for (int i = 0; i < 16; i++){
    int idx = wid * 16 + i;
    racc += ebuf[idx] * out[(size_t)(n0 + idx) * 64 + lane];
  }
  rpart[wid][lane] = racc;
  __syncthreads();
  if (wid == 0){
    float rt = rpart[0][lane] + rpart[1][lane] + rpart[2][lane] + rpart[3][lane];
    atomicAdd(&scal[128 + lane], rt);
  } else if (wid == 1){
    float es = wred(ebuf[lane]);
    if (lane == 0) atomicAdd(&scal[193], es);
  }
}

// memory LSTM + value head, wave-parallel gates.
__global__ __launch_bounds__(256) void k_memlstm(const float* __restrict__ Wih,
    const float* __restrict__ Whh, const float* __restrict__ bih,
    const float* __restrict__ bhh, const float* __restrict__ hx,
    const float* __restrict__ cx, const float* __restrict__ W3,
    const float* __restrict__ b3, float* __restrict__ scal, float* __restrict__ dout)
{
  __shared__ float pool[128];
  __shared__ float hxs[64];
  __shared__ float gsh[4][64];
  __shared__ float lob[64];
  int tid = threadIdx.x, gg = tid >> 6, lane = tid & 63;
  if (gg == 0){
    pool[lane] = scal[lane];
    pool[64 + lane] = scal[128 + lane] / scal[193];
    hxs[lane] = hx[lane];
  }
  __syncthreads();
  float2 fq = *(const float2*)&pool[2 * lane];
  float hv = hxs[lane];
  #pragma unroll 4
  for (int o = 0; o < 64; o++){
    int row = gg * 64 + o;
    float2 wv = *(const float2*)&Wih[(size_t)row * 128 + 2 * lane];
    float s = wv.x * fq.x + wv.y * fq.y + Whh[(size_t)row * 64 + lane] * hv;
    s = wred(s);
    if (lane == 0) gsh[gg][o] = s;
  }
  __syncthreads();
  if (gg == 0){
    float gi = gsh[0][lane] + bih[lane]       + bhh[lane];
    float gf = gsh[1][lane] + bih[64 + lane]  + bhh[64 + lane];
    float gv = gsh[2][lane] + bih[128 + lane] + bhh[128 + lane];
    float go = gsh[3][lane] + bih[192 + lane] + bhh[192 + lane];
    float cn = sigm(gf) * cx[lane] + sigm(gi) * tanhf(gv);
    float hn = sigm(go) * tanhf(cn);
    dout[12289 + lane] = hn;     // hx_new
    dout[12353 + lane] = cn;     // cx_new
    scal[256 + lane] = hn;       // lstm_out for head
    lob[lane] = hn;
  }
  __syncthreads();
  if (gg == 0){
    float a = pool[lane] * W3[lane] + pool[64 + lane] * W3[64 + lane]
            + lob[lane] * W3[128 + lane];
    a = wred(a);
    if (lane == 0) dout[12288] = a + b3[0];
  }
}

// torsion head. pf[t, j<256] = out[nr[j*32 + t/64], t%64]; pf[t, 256..319] = lstm_out[t>>5]
__global__ __launch_bounds__(256) void k_head(const float* __restrict__ out,
    const int* __restrict__ nr, const float* __restrict__ scal,
    const float* __restrict__ W1, const float* __restrict__ b1,
    const float* __restrict__ W2, const float* __restrict__ b2,
    float* __restrict__ dout)
{
  __shared__ float pf[4][320];
  __shared__ float hb[4][64];
  int tid = threadIdx.x, wid = tid >> 6, lane = tid & 63;
  int t = blockIdx.x * 4 + wid;
  float lo = scal[256 + (t >> 5)];
  #pragma unroll
  for (int rep = 0; rep < 4; rep++){
    int j = rep * 64 + lane;
    int idx = nr[j * 32 + (t >> 6)];
    pf[wid][j] = out[idx * 64 + (t & 63)];
  }
  pf[wid][256 + lane] = lo;
  __syncthreads();
  float acc = b1[lane];
  const float* w = W1 + lane * 320;
  #pragma unroll 4
  for (int j = 0; j < 320; j++) acc += pf[wid][j] * w[j];
  hb[wid][lane] = fmaxf(acc, 0.f);
  __syncthreads();
  if (lane < 6){
    float a2 = b2[lane];
    const float* w2 = W2 + lane * 64;
    #pragma unroll 4
    for (int f = 0; f < 64; f++) a2 += hb[wid][f] * w2[f];
    dout[t * 6 + lane] = a2;
  }
}

extern "C" void kernel_launch(void* const* d_in, const int* in_sizes, int n_in,
                              void* d_out, int out_size, void* d_ws, size_t ws_size,
                              hipStream_t stream)
{
  const float* x         = (const float*)d_in[0];
  const float* edge_attr = (const float*)d_in[1];
  const int*   ei        = (const int*)d_in[2];
  const int*   nonring   = (const int*)d_in[3];
  const float* hx        = (const float*)d_in[4];
  const float* cx        = (const float*)d_in[5];
  const float* W_lin0 = (const float*)d_in[6];  const float* b_lin0 = (const float*)d_in[7];
  const float* W_e1   = (const float*)d_in[8];  const float* b_e1   = (const float*)d_in[9];
  const float* W_e2   = (const float*)d_in[10]; const float* b_e2   = (const float*)d_in[11];
  const float* convW  = (const float*)d_in[12]; const float* convB  = (const float*)d_in[13];
  const float* gWih   = (const float*)d_in[14]; const float* gWhh   = (const float*)d_in[15];
  const float* gbih   = (const float*)d_in[16]; const float* gbhh   = (const float*)d_in[17];
  const float* sWih   = (const float*)d_in[18]; const float* sWhh   = (const float*)d_in[19];
  const float* sbih   = (const float*)d_in[20]; const float* sbhh   = (const float*)d_in[21];
  const float* mWih   = (const float*)d_in[22]; const float* mWhh   = (const float*)d_in[23];
  const float* mbih   = (const float*)d_in[24]; const float* mbhh   = (const float*)d_in[25];
  const float* W_lin1 = (const float*)d_in[26]; const float* b_lin1 = (const float*)d_in[27];
  const float* W_lin2 = (const float*)d_in[28]; const float* b_lin2 = (const float*)d_in[29];
  const float* W_lin3 = (const float*)d_in[30]; const float* b_lin3 = (const float*)d_in[31];
  float* dout = (float*)d_out;

  char* w = (char*)d_ws;
  float* outb = (float*)w;  w += (size_t)cN * 64 * 4;
  float* aggr = (float*)w;  w += (size_t)cN * 64 * 4;
  short* h1   = (short*)w;  w += (size_t)cE * 128 * 2;
  short* w2f  = (short*)w;  w += (size_t)64 * 8192 * 2;
  short* b2f  = (short*)w;  w += 4096 * 2;
  float* cntb = (float*)w;  w += cN * 4;
  float* sbuf = (float*)w;  w += cN * 4;
  float* scal = (float*)w;  w += 512 * 4;
  int* deg  = (int*)w;  w += cN * 4;
  int* cur  = (int*)w;  w += cN * 4;
  int* rowp = (int*)w;  w += (cN + 1) * 4 + 60;   // keep alignment
  int* esrc = (int*)w;  w += cE * 4;
  int* eidx = (int*)w;  w += cE * 4;

  hipMemsetAsync(deg, 0, cN * 4, stream);
  hipMemsetAsync(cur, 0, cN * 4, stream);

  k_lin0<<<cN * 64 / 256, 256, 0, stream>>>(x, W_lin0, b_lin0, outb);
  k_h1<<<cE * 128 / 256, 256, 0, stream>>>(edge_attr, W_e1, b_e1, h1);
  k_w2f<<<64 * 8192 / 256, 256, 0, stream>>>(W_e2, w2f);
  k_b2f<<<16, 256, 0, stream>>>(b_e2, b2f);
  k_deg<<<cE / 256, 256, 0, stream>>>(ei, deg);
  k_scan<<<1, 1024, 0, stream>>>(deg, rowp, cntb);
  k_scatter<<<cE / 256, 256, 0, stream>>>(ei, rowp, cur, esrc, eidx);

  for (int it = 0; it < 3; it++){
    k_sagg<<<cN / 16, 256, 0, stream>>>(outb, h1, w2f, b2f, rowp, esrc, eidx, aggr);
    k_node<<<256, 512, 0, stream>>>(outb, aggr, cntb, convW, convB, gWih, gWhh, gbih, gbhh);
  }

  for (int st = 0; st < 3; st++){
    k_s2s_lstm<<<1, 256, 0, stream>>>(sWih, sWhh, sbih, sbhh, scal, st == 0 ? 1 : 0);
    k_dots<<<cN / 64, 256, 0, stream>>>(outb, scal, sbuf);
    k_sm<<<cN / 64, 256, 0, stream>>>(outb, sbuf, scal);
  }

  k_memlstm<<<1, 256, 0, stream>>>(mWih, mWhh, mbih, mbhh, hx, cx, W_lin3, b_lin3, scal, dout);
  k_head<<<cT / 4, 256, 0, stream>>>(outb, nonring, scal, W_lin1, b_lin1, W_lin2, b_lin2, dout);
}

// Round 6
// 601.361 us; speedup vs baseline: 3.1387x; 1.1181x over previous
//
#include <hip/hip_runtime.h>

#define cN 16384
#define cE 65536
#define cT 2048
#define CAP 78

typedef __attribute__((ext_vector_type(8))) short short8;
typedef __attribute__((ext_vector_type(4))) float f32x4;
typedef __attribute__((ext_vector_type(4))) unsigned u32x4;

__device__ __forceinline__ short f2bf(float f){
  unsigned u = __float_as_uint(f);
  u = (u + 0x7FFFu + ((u >> 16) & 1u)) >> 16;
  return (short)u;
}
__device__ __forceinline__ float bf2f(short s){
  return __uint_as_float(((unsigned)(unsigned short)s) << 16);
}
__device__ __forceinline__ unsigned cvtpk(float lo, float hi){
  unsigned r;
  asm("v_cvt_pk_bf16_f32 %0, %1, %2" : "=v"(r) : "v"(lo), "v"(hi));
  return r;
}
__device__ __forceinline__ float sigm(float x){ return 1.f / (1.f + __expf(-x)); }
__device__ __forceinline__ unsigned fenc(float f){
  unsigned u = __float_as_uint(f);
  return (u & 0x80000000u) ? ~u : (u | 0x80000000u);
}
__device__ __forceinline__ float fdec(unsigned u){
  u = (u & 0x80000000u) ? (u & 0x7FFFFFFFu) : ~u;
  return __uint_as_float(u);
}
__device__ __forceinline__ float wred(float v){
  v += __shfl_xor(v, 32); v += __shfl_xor(v, 16); v += __shfl_xor(v, 8);
  v += __shfl_xor(v, 4);  v += __shfl_xor(v, 2);  v += __shfl_xor(v, 1);
  return v;
}

// out = relu(x @ W_lin0.T + b)
__global__ __launch_bounds__(256) void k_lin0(const float* __restrict__ x,
    const float* __restrict__ W, const float* __restrict__ b, float* __restrict__ out)
{
  int i = blockIdx.x * 256 + threadIdx.x;       // cN*64
  int n = i >> 6, f = i & 63;
  float acc = b[f] + x[n*3]*W[f*3] + x[n*3+1]*W[f*3+1] + x[n*3+2]*W[f*3+2];
  out[i] = fmaxf(acc, 0.f);
}

// h1 = bf16(relu(edge_attr @ W_e1.T + b_e1))
__global__ __launch_bounds__(256) void k_h1(const float* __restrict__ ea,
    const float* __restrict__ W, const float* __restrict__ b, short* __restrict__ h1)
{
  int i = blockIdx.x * 256 + threadIdx.x;       // cE*128
  int e = i >> 7, k = i & 127;
  const float* a = ea + e * 7;
  const float* w = W + k * 7;
  float acc = b[k];
  #pragma unroll
  for (int c = 0; c < 7; c++) acc += a[c] * w[c];
  h1[i] = f2bf(fmaxf(acc, 0.f));
}

// W2 -> fragment-major bf16 layout, chunk-local k-major element order:
// col-in-chunk pos = ks*32 + kg*8 + j  <->  (k = ks*4 + kg, d = c*8 + j)
__global__ __launch_bounds__(256) void k_w2f(const float* __restrict__ W2, short* __restrict__ w2f)
{
  int o = blockIdx.x * 256 + threadIdx.x;       // 524288
  int j = o & 7, l = (o >> 3) & 63, ks = (o >> 9) & 31, c = (o >> 14) & 7, fb = (o >> 17) & 3;
  int f = fb * 16 + (l & 15);
  int d = c * 8 + j;
  int k = ks * 4 + ((l >> 4) & 3);
  w2f[o] = f2bf(W2[(d * 64 + f) * 128 + k]);
}

// b2 -> B-fragment layout for the bias MFMA (d = ks2*32 + kg*8 + j)
__global__ __launch_bounds__(256) void k_b2f(const float* __restrict__ b2, short* __restrict__ b2f)
{
  int o = blockIdx.x * 256 + threadIdx.x;       // 4096
  int j = o & 7, l = (o >> 3) & 63, ks2 = (o >> 9) & 1, fb = (o >> 10) & 3;
  int d = ks2 * 32 + ((l >> 4) & 3) * 8 + j;
  int f = fb * 16 + (l & 15);
  b2f[o] = f2bf(b2[d * 64 + f]);
}

// pack conv_root / gru_Wih / gru_Whh into B-fragment layout (28 col-blocks of 16):
// cb 0..3: conv (B[k=d][f]=convW[d*64+f]); cb 4..15: Wih (B[d][gf]=Wih[gf*64+d]);
// cb 16..27: Whh. offset = ((cb*2+kc)*64 + l)*8 + j, k = kc*32+((l>>4)&3)*8+j.
__global__ __launch_bounds__(256) void k_wpack(const float* __restrict__ convW,
    const float* __restrict__ Wih, const float* __restrict__ Whh, short* __restrict__ wpk)
{
  int o = blockIdx.x * 256 + threadIdx.x;       // 28672
  int j = o & 7, l = (o >> 3) & 63, kc = (o >> 9) & 1, cb = o >> 10;
  int k = kc * 32 + ((l >> 4) & 3) * 8 + j;
  int c16 = l & 15;
  float v;
  if (cb < 4)       v = convW[k * 64 + cb * 16 + c16];
  else if (cb < 16) v = Wih[((cb - 4) * 16 + c16) * 64 + k];
  else              v = Whh[((cb - 16) * 16 + c16) * 64 + k];
  wpk[o] = f2bf(v);
}

__global__ __launch_bounds__(256) void k_deg(const int* __restrict__ ei, int* __restrict__ deg)
{
  int e = blockIdx.x * 256 + threadIdx.x;
  atomicAdd(&deg[ei[cE + e]], 1);
}

// exclusive scan over 16384 degrees; also fills cnt = max(deg,1)
__global__ __launch_bounds__(1024) void k_scan(const int* __restrict__ deg,
    int* __restrict__ rowp, float* __restrict__ cnt)
{
  __shared__ int part[1024];
  int tid = threadIdx.x;
  int base = tid * 16;
  int loc[16]; int s = 0;
  #pragma unroll
  for (int i = 0; i < 16; i++){ loc[i] = s; s += deg[base + i]; }
  part[tid] = s;
  __syncthreads();
  for (int off = 1; off < 1024; off <<= 1){
    int v = (tid >= off) ? part[tid - off] : 0;
    __syncthreads();
    part[tid] += v;
    __syncthreads();
  }
  int inc = part[tid];
  int eb = inc - s;
  #pragma unroll
  for (int i = 0; i < 16; i++){
    rowp[base + i] = eb + loc[i];
    int dv = deg[base + i];
    cnt[base + i] = (float)(dv > 0 ? dv : 1);
  }
  if (tid == 1023) rowp[16384] = inc;
}

__global__ __launch_bounds__(256) void k_scatter(const int* __restrict__ ei,
    const int* __restrict__ rowp, int* __restrict__ cur,
    int* __restrict__ esrc, int* __restrict__ eidx)
{
  int e = blockIdx.x * 256 + threadIdx.x;
  int t = ei[cE + e];
  int pos = rowp[t] + atomicAdd(&cur[t], 1);
  esrc[pos] = ei[e];
  eidx[pos] = e;
}

// Fused bilinear aggregation.
// aggr[t,f] = sum_{d,k} S_t[d,k]*W2[(d,f),k] + sum_d os_t[d]*b2[d*64+f]  (raw; /cnt later)
__global__ __launch_bounds__(256) void k_sagg(const float* __restrict__ out,
    const short* __restrict__ h1, const short* __restrict__ w2f,
    const short* __restrict__ b2f, const int* __restrict__ rowp,
    const int* __restrict__ esrc, const int* __restrict__ eidx,
    float* __restrict__ aggr)
{
  __shared__ __align__(16) short S[16][1040];       // chunk-local pos = k*8 + d
  __shared__ __align__(16) unsigned h1i[CAP][64];   // packed (h1[k=lane], h1[k=64+lane])
  __shared__ __align__(16) float outsf[CAP][64];
  __shared__ __align__(16) short osb[16][72];
  int tid = threadIdx.x, w = tid >> 6, lane = tid & 63;
  int t0 = blockIdx.x * 16;

  int ebase = rowp[t0];
  int eend  = rowp[t0 + 16];
  int ecnt  = eend - ebase;
  bool fits = (ecnt <= CAP);
  int scnt  = fits ? ecnt : CAP;
  // ---- stage edge data once (coalesced) ----
  for (int i = w; i < scnt; i += 4){
    int eid = eidx[ebase + i];
    int src = esrc[ebase + i];
    unsigned lo = (unsigned short)h1[(size_t)eid * 128 + lane];
    unsigned hi = (unsigned short)h1[(size_t)eid * 128 + 64 + lane];
    h1i[i][lane] = lo | (hi << 16);
    outsf[i][lane] = out[(size_t)src * 64 + lane];
  }
  // per-wave target slices
  int toff[4], tcnt[4];
  #pragma unroll
  for (int g = 0; g < 4; g++){
    int t = t0 + w * 4 + g;
    int a = rowp[t], b = rowp[t + 1];
    toff[g] = a - ebase; tcnt[g] = b - a;
  }
  __syncthreads();

  // ---- os_t[d] once (lane = d), bf16 into osb ----
  #pragma unroll
  for (int g = 0; g < 4; g++){
    int ti = w * 4 + g;
    float os = 0.f;
    int tf = toff[g], tc = tcnt[g];
    for (int p = 0; p < tc; p++){
      int slot = tf + p;
      if (slot < CAP) os += outsf[slot][lane];
      else            os += out[(size_t)esrc[ebase + slot] * 64 + lane];
    }
    osb[ti][lane] = (short)cvtpk(os, os);
  }

  f32x4 acc = {0.f, 0.f, 0.f, 0.f};
  int arow = lane & 15, kg = lane >> 4;
  for (int c = 0; c < 8; ++c){
    // ---- phase A: accumulate S-slice (d = c*8 .. c*8+7; k = lane / 64+lane) ----
    #pragma unroll
    for (int g = 0; g < 4; ++g){
      int ti = w * 4 + g;
      float a0[8], a1[8];
      #pragma unroll
      for (int d = 0; d < 8; d++){ a0[d] = 0.f; a1[d] = 0.f; }
      int tc = tcnt[g], tf = toff[g];
      if (fits){
        #pragma unroll 2
        for (int p = 0; p < tc; ++p){
          int slot = tf + p;
          unsigned u = h1i[slot][lane];
          float h1a = __uint_as_float(u << 16);
          float h1b = __uint_as_float(u & 0xFFFF0000u);
          f32x4 o0 = *(const f32x4*)&outsf[slot][c * 8];
          f32x4 o1 = *(const f32x4*)&outsf[slot][c * 8 + 4];
          a0[0] = fmaf(o0[0], h1a, a0[0]); a1[0] = fmaf(o0[0], h1b, a1[0]);
          a0[1] = fmaf(o0[1], h1a, a0[1]); a1[1] = fmaf(o0[1], h1b, a1[1]);
          a0[2] = fmaf(o0[2], h1a, a0[2]); a1[2] = fmaf(o0[2], h1b, a1[2]);
          a0[3] = fmaf(o0[3], h1a, a0[3]); a1[3] = fmaf(o0[3], h1b, a1[3]);
          a0[4] = fmaf(o1[0], h1a, a0[4]); a1[4] = fmaf(o1[0], h1b, a1[4]);
          a0[5] = fmaf(o1[1], h1a, a0[5]); a1[5] = fmaf(o1[1], h1b, a1[5]);
          a0[6] = fmaf(o1[2], h1a, a0[6]); a1[6] = fmaf(o1[2], h1b, a1[6]);
          a0[7] = fmaf(o1[3], h1a, a0[7]); a1[7] = fmaf(o1[3], h1b, a1[7]);
        }
      } else {
        for (int p = 0; p < tc; ++p){
          int slot = tf + p;
          float h1a, h1b;
          if (slot < CAP){
            unsigned u = h1i[slot][lane];
            h1a = __uint_as_float(u << 16);
            h1b = __uint_as_float(u & 0xFFFF0000u);
            f32x4 o0 = *(const f32x4*)&outsf[slot][c * 8];
            f32x4 o1 = *(const f32x4*)&outsf[slot][c * 8 + 4];
            #pragma unroll
            for (int d = 0; d < 4; d++){
              a0[d] = fmaf(o0[d], h1a, a0[d]); a1[d] = fmaf(o0[d], h1b, a1[d]);
              a0[4+d] = fmaf(o1[d], h1a, a0[4+d]); a1[4+d] = fmaf(o1[d], h1b, a1[4+d]);
            }
          } else {
            int eid = eidx[ebase + slot];
            int src = esrc[ebase + slot];
            h1a = bf2f(h1[(size_t)eid * 128 + lane]);
            h1b = bf2f(h1[(size_t)eid * 128 + 64 + lane]);
            #pragma unroll
            for (int d = 0; d < 8; d++){
              float o = out[(size_t)src * 64 + c * 8 + d];
              a0[d] = fmaf(o, h1a, a0[d]); a1[d] = fmaf(o, h1b, a1[d]);
            }
          }
        }
      }
      // S writes: k-major pos = k*8+d; one b128 per k (k=lane and k=64+lane)
      u32x4 p0, p1;
      p0[0] = cvtpk(a0[0], a0[1]); p0[1] = cvtpk(a0[2], a0[3]);
      p0[2] = cvtpk(a0[4], a0[5]); p0[3] = cvtpk(a0[6], a0[7]);
      p1[0] = cvtpk(a1[0], a1[1]); p1[1] = cvtpk(a1[2], a1[3]);
      p1[2] = cvtpk(a1[4], a1[5]); p1[3] = cvtpk(a1[6], a1[7]);
      *(u32x4*)&S[ti][lane * 8]       = p0;
      *(u32x4*)&S[ti][512 + lane * 8] = p1;
    }
    __syncthreads();
    // ---- phase B: MFMA contraction for this chunk (1024 elements) ----
    const short* bbase = w2f + ((size_t)(w * 8 + c) * 32) * 512 + lane * 8;
    #pragma unroll
    for (int ks = 0; ks < 32; ++ks){
      short8 afr = *(const short8*)&S[arow][ks * 32 + kg * 8];
      short8 bfr = *(const short8*)(bbase + (size_t)ks * 512);
      acc = __builtin_amdgcn_mfma_f32_16x16x32_bf16(afr, bfr, acc, 0, 0, 0);
    }
    __syncthreads();
  }
  // ---- bias term as 2 MFMA steps: acc += os @ B2 ----
  #pragma unroll
  for (int ks2 = 0; ks2 < 2; ++ks2){
    short8 osf = *(const short8*)&osb[arow][ks2 * 32 + kg * 8];
    short8 bfr = *(const short8*)(b2f + ((size_t)((w * 2 + ks2) * 64 + lane)) * 8);
    acc = __builtin_amdgcn_mfma_f32_16x16x32_bf16(osf, bfr, acc, 0, 0, 0);
  }
  // ---- store raw sums ----
  int fcol = w * 16 + arow;
  int trow = kg * 4;
  #pragma unroll
  for (int q = 0; q < 4; q++)
    aggr[(size_t)(t0 + trow + q) * 64 + fcol] = acc[q];
}

// MFMA node update: m = relu(aggr/cnt + out@conv + cb); GRU(m, out) -> out.
// 64 nodes/block, 4 waves (wave w = rows w*16..w*16+15).
__global__ __launch_bounds__(256) void k_nodeM(float* __restrict__ out,
    const float* __restrict__ aggr, const float* __restrict__ cnt,
    const short* __restrict__ wpk, const float* __restrict__ convB,
    const float* __restrict__ bih, const float* __restrict__ bhh)
{
  __shared__ __align__(16) short outA[64][72];
  __shared__ __align__(16) short mA[64][72];
  __shared__ float sb[448];
  const short8* WF = (const short8*)wpk;
  int tid = threadIdx.x, w = tid >> 6, lane = tid & 63;
  int n0 = blockIdx.x * 64;
  // stage out tile (f32 -> bf16, packed u32 writes)
  for (int i = tid; i < 2048; i += 256){
    int r = i >> 5, c2 = (i & 31) * 2;
    float2 v = *(const float2*)&out[(size_t)(n0 + r) * 64 + c2];
    *(unsigned*)&outA[r][c2] = cvtpk(v.x, v.y);
  }
  if (tid < 64) sb[tid] = convB[tid];
  for (int i = tid; i < 192; i += 256){ sb[64 + i] = bih[i]; sb[256 + i] = bhh[i]; }
  __syncthreads();
  int arow = lane & 15, kg = lane >> 4;
  int r0 = w * 16;
  short8 aof0 = *(const short8*)&outA[r0 + arow][kg * 8];
  short8 aof1 = *(const short8*)&outA[r0 + arow][32 + kg * 8];
  float ic[4];
  #pragma unroll
  for (int q = 0; q < 4; q++)
    ic[q] = 1.0f / fmaxf(cnt[n0 + r0 + kg * 4 + q], 1.0f);
  // stage 1: conv -> m
  #pragma unroll
  for (int cf = 0; cf < 4; cf++){
    f32x4 a = {0.f, 0.f, 0.f, 0.f};
    a = __builtin_amdgcn_mfma_f32_16x16x32_bf16(aof0, WF[(cf * 2 + 0) * 64 + lane], a, 0, 0, 0);
    a = __builtin_amdgcn_mfma_f32_16x16x32_bf16(aof1, WF[(cf * 2 + 1) * 64 + lane], a, 0, 0, 0);
    int col = cf * 16 + arow;
    float cb_ = sb[col];
    #pragma unroll
    for (int q = 0; q < 4; q++){
      int r = n0 + r0 + kg * 4 + q;
      float m = fmaxf(aggr[(size_t)r * 64 + col] * ic[q] + a[q] + cb_, 0.f);
      mA[r0 + kg * 4 + q][col] = f2bf(m);
    }
  }
  __syncthreads();
  short8 amf0 = *(const short8*)&mA[r0 + arow][kg * 8];
  short8 amf1 = *(const short8*)&mA[r0 + arow][32 + kg * 8];
  // stage 2: gates per 16-col block (keeps VGPR low)
  #pragma unroll
  for (int co = 0; co < 4; co++){
    f32x4 gir = {0,0,0,0}, giz = {0,0,0,0}, gin = {0,0,0,0};
    f32x4 ghr = {0,0,0,0}, ghz = {0,0,0,0}, ghn = {0,0,0,0};
    gir = __builtin_amdgcn_mfma_f32_16x16x32_bf16(amf0, WF[((4  + co) * 2 + 0) * 64 + lane], gir, 0, 0, 0);
    gir = __builtin_amdgcn_mfma_f32_16x16x32_bf16(amf1, WF[((4  + co) * 2 + 1) * 64 + lane], gir, 0, 0, 0);
    giz = __builtin_amdgcn_mfma_f32_16x16x32_bf16(amf0, WF[((8  + co) * 2 + 0) * 64 + lane], giz, 0, 0, 0);
    giz = __builtin_amdgcn_mfma_f32_16x16x32_bf16(amf1, WF[((8  + co) * 2 + 1) * 64 + lane], giz, 0, 0, 0);
    gin = __builtin_amdgcn_mfma_f32_16x16x32_bf16(amf0, WF[((12 + co) * 2 + 0) * 64 + lane], gin, 0, 0, 0);
    gin = __builtin_amdgcn_mfma_f32_16x16x32_bf16(amf1, WF[((12 + co) * 2 + 1) * 64 + lane], gin, 0, 0, 0);
    ghr = __builtin_amdgcn_mfma_f32_16x16x32_bf16(aof0, WF[((16 + co) * 2 + 0) * 64 + lane], ghr, 0, 0, 0);
    ghr = __builtin_amdgcn_mfma_f32_16x16x32_bf16(aof1, WF[((16 + co) * 2 + 1) * 64 + lane], ghr, 0, 0, 0);
    ghz = __builtin_amdgcn_mfma_f32_16x16x32_bf16(aof0, WF[((20 + co) * 2 + 0) * 64 + lane], ghz, 0, 0, 0);
    ghz = __builtin_amdgcn_mfma_f32_16x16x32_bf16(aof1, WF[((20 + co) * 2 + 1) * 64 + lane], ghz, 0, 0, 0);
    ghn = __builtin_amdgcn_mfma_f32_16x16x32_bf16(aof0, WF[((24 + co) * 2 + 0) * 64 + lane], ghn, 0, 0, 0);
    ghn = __builtin_amdgcn_mfma_f32_16x16x32_bf16(aof1, WF[((24 + co) * 2 + 1) * 64 + lane], ghn, 0, 0, 0);
    int col = co * 16 + arow;
    float bir = sb[64 + col],  biz = sb[128 + col], bin_ = sb[192 + col];
    float bhr = sb[256 + col], bhz = sb[320 + col], bhn = sb[384 + col];
    #pragma unroll
    for (int q = 0; q < 4; q++){
      size_t r = (size_t)(n0 + r0 + kg * 4 + q);
      float rr = sigm(gir[q] + bir + ghr[q] + bhr);
      float zz = sigm(giz[q] + biz + ghz[q] + bhz);
      float nn = tanhf(gin[q] + bin_ + rr * (ghn[q] + bhn));
      float o = out[r * 64 + col];
      out[r * 64 + col] = (1.f - zz) * nn + zz * o;
    }
  }
}

// Fused Set2Set step: LSTM (redundant per block) + dots + block max + global atomicMax.
// State paged: page p = scal + p*256: [0..63]=hs, [64..127]=cs, [128..191]=r_raw,
// [192]=gmax(u32, fenc), [193]=esum.  Pages pre-zeroed each launch.
__global__ __launch_bounds__(256) void k_dotsF(const float* __restrict__ out,
    const float* __restrict__ Wih, const float* __restrict__ Whh,
    const float* __restrict__ bih, const float* __restrict__ bhh,
    float* __restrict__ scal, float* __restrict__ sbuf, int st)
{
  __shared__ float q[128];
  __shared__ float hsL[64];
  __shared__ float gsh[4][64];
  __shared__ float hsh[64];
  __shared__ float smax[4];
  const float* pg = scal + st * 256;
  float* pn = scal + (st + 1) * 256;
  int tid = threadIdx.x, gg = tid >> 6, lane = tid & 63;
  if (gg == 0){
    float hs = pg[lane];
    float es = pg[193];
    float rv = (es == 0.f) ? 0.f : pg[128 + lane] / es;
    q[lane] = hs; q[64 + lane] = rv; hsL[lane] = hs;
  }
  __syncthreads();
  float2 fq = *(const float2*)&q[2 * lane];
  float hv0 = hsL[lane];
  #pragma unroll 4
  for (int o = 0; o < 64; o++){
    int row = gg * 64 + o;
    float2 wv = *(const float2*)&Wih[(size_t)row * 128 + 2 * lane];
    float s = wv.x * fq.x + wv.y * fq.y + Whh[(size_t)row * 64 + lane] * hv0;
    s = wred(s);
    if (lane == 0) gsh[gg][o] = s;
  }
  __syncthreads();
  if (gg == 0){
    float gi = gsh[0][lane] + bih[lane]       + bhh[lane];
    float gf = gsh[1][lane] + bih[64 + lane]  + bhh[64 + lane];
    float gv = gsh[2][lane] + bih[128 + lane] + bhh[128 + lane];
    float go = gsh[3][lane] + bih[192 + lane] + bhh[192 + lane];
    float cs = pg[64 + lane];
    float cn = sigm(gf) * cs + sigm(gi) * tanhf(gv);
    float hn = sigm(go) * tanhf(cn);
    hsh[lane] = hn;
    if (blockIdx.x == 0){ pn[lane] = hn; pn[64 + lane] = cn; }
  }
  __syncthreads();
  int nbase = blockIdx.x * 64 + gg * 16;
  float hv = hsh[lane];
  float wmax = -3.4e38f;
  #pragma unroll 4
  for (int i = 0; i < 16; i++){
    int n = nbase + i;
    float p = wred(out[(size_t)n * 64 + lane] * hv);
    if (lane == 0) sbuf[n] = p;
    wmax = fmaxf(wmax, p);
  }
  if (lane == 0) smax[gg] = wmax;
  __syncthreads();
  if (tid == 0){
    float m = fmaxf(fmaxf(smax[0], smax[1]), fmaxf(smax[2], smax[3]));
    atomicMax((unsigned*)(pn + 192), fenc(m));
  }
}

// e = exp(s - gmax); accumulate esum and r_raw into page st+1.  64 nodes/block.
__global__ __launch_bounds__(256) void k_smF(const float* __restrict__ out,
    const float* __restrict__ sbuf, float* __restrict__ scal, int st)
{
  float* pn = scal + (st + 1) * 256;
  __shared__ float ebuf[64];
  __shared__ float rpart[4][64];
  int tid = threadIdx.x, wid = tid >> 6, lane = tid & 63;
  float gm = fdec(((const unsigned*)pn)[192]);
  int n0 = blockIdx.x * 64;
  if (tid < 64) ebuf[tid] = __expf(sbuf[n0 + tid] - gm);
  __syncthreads();
  float racc = 0.f;
  #pragma unroll 4
  for (int i = 0; i < 16; i++){
    int idx = wid * 16 + i;
    racc += ebuf[idx] * out[(size_t)(n0 + idx) * 64 + lane];
  }
  rpart[wid][lane] = racc;
  __syncthreads();
  if (wid == 0){
    float rt = rpart[0][lane] + rpart[1][lane] + rpart[2][lane] + rpart[3][lane];
    atomicAdd(&pn[128 + lane], rt);
  } else if (wid == 1){
    float es = wred(ebuf[lane]);
    if (lane == 0) atomicAdd(&pn[193], es);
  }
}

// memory LSTM + value head, wave-parallel gates. Reads page 3; lstm_out -> scal[1024..]
__global__ __launch_bounds__(256) void k_memlstm(const float* __restrict__ Wih,
    const float* __restrict__ Whh, const float* __restrict__ bih,
    const float* __restrict__ bhh, const float* __restrict__ hx,
    const float* __restrict__ cx, const float* __restrict__ W3,
    const float* __restrict__ b3, float* __restrict__ scal, float* __restrict__ dout)
{
  __shared__ float pool[128];
  __shared__ float hxs[64];
  __shared__ float gsh[4][64];
  __shared__ float lob[64];
  const float* pg = scal + 3 * 256;
  int tid = threadIdx.x, gg = tid >> 6, lane = tid & 63;
  if (gg == 0){
    pool[lane] = pg[lane];
    pool[64 + lane] = pg[128 + lane] / pg[193];
    hxs[lane] = hx[lane];
  }
  __syncthreads();
  float2 fq = *(const float2*)&pool[2 * lane];
  float hv = hxs[lane];
  #pragma unroll 4
  for (int o = 0; o < 64; o++){
    int row = gg * 64 + o;
    float2 wv = *(const float2*)&Wih[(size_t)row * 128 + 2 * lane];
    float s = wv.x * fq.x + wv.y * fq.y + Whh[(size_t)row * 64 + lane] * hv;
    s = wred(s);
    if (lane == 0) gsh[gg][o] = s;
  }
  __syncthreads();
  if (gg == 0){
    float gi = gsh[0][lane] + bih[lane]       + bhh[lane];
    float gf = gsh[1][lane] + bih[64 + lane]  + bhh[64 + lane];
    float gv = gsh[2][lane] + bih[128 + lane] + bhh[128 + lane];
    float go = gsh[3][lane] + bih[192 + lane] + bhh[192 + lane];
    float cn = sigm(gf) * cx[lane] + sigm(gi) * tanhf(gv);
    float hn = sigm(go) * tanhf(cn);
    dout[12289 + lane] = hn;     // hx_new
    dout[12353 + lane] = cn;     // cx_new
    scal[1024 + lane] = hn;      // lstm_out for head
    lob[lane] = hn;
  }
  __syncthreads();
  if (gg == 0){
    float a = pool[lane] * W3[lane] + pool[64 + lane] * W3[64 + lane]
            + lob[lane] * W3[128 + lane];
    a = wred(a);
    if (lane == 0) dout[12288] = a + b3[0];
  }
}

// torsion head. pf[t, j<256] = out[nr[j*32 + t/64], t%64]; pf[t, 256..319] = lstm_out[t>>5]
__global__ __launch_bounds__(256) void k_head(const float* __restrict__ out,
    const int* __restrict__ nr, const float* __restrict__ scal,
    const float* __restrict__ W1, const float* __restrict__ b1,
    const float* __restrict__ W2, const float* __restrict__ b2,
    float* __restrict__ dout)
{
  __shared__ float pf[4][320];
  __shared__ float hb[4][64];
  int tid = threadIdx.x, wid = tid >> 6, lane = tid & 63;
  int t = blockIdx.x * 4 + wid;
  float lo = scal[1024 + (t >> 5)];
  #pragma unroll
  for (int rep = 0; rep < 4; rep++){
    int j = rep * 64 + lane;
    int idx = nr[j * 32 + (t >> 6)];
    pf[wid][j] = out[idx * 64 + (t & 63)];
  }
  pf[wid][256 + lane] = lo;
  __syncthreads();
  float acc = b1[lane];
  const float* w = W1 + lane * 320;
  #pragma unroll 4
  for (int j = 0; j < 320; j++) acc += pf[wid][j] * w[j];
  hb[wid][lane] = fmaxf(acc, 0.f);
  __syncthreads();
  if (lane < 6){
    float a2 = b2[lane];
    const float* w2 = W2 + lane * 64;
    #pragma unroll 4
    for (int f = 0; f < 64; f++) a2 += hb[wid][f] * w2[f];
    dout[t * 6 + lane] = a2;
  }
}

extern "C" void kernel_launch(void* const* d_in, const int* in_sizes, int n_in,
                              void* d_out, int out_size, void* d_ws, size_t ws_size,
                              hipStream_t stream)
{
  const float* x         = (const float*)d_in[0];
  const float* edge_attr = (const float*)d_in[1];
  const int*   ei        = (const int*)d_in[2];
  const int*   nonring   = (const int*)d_in[3];
  const float* hx        = (const float*)d_in[4];
  const float* cx        = (const float*)d_in[5];
  const float* W_lin0 = (const float*)d_in[6];  const float* b_lin0 = (const float*)d_in[7];
  const float* W_e1   = (const float*)d_in[8];  const float* b_e1   = (const float*)d_in[9];
  const float* W_e2   = (const float*)d_in[10]; const float* b_e2   = (const float*)d_in[11];
  const float* convW  = (const float*)d_in[12]; const float* convB  = (const float*)d_in[13];
  const float* gWih   = (const float*)d_in[14]; const float* gWhh   = (const float*)d_in[15];
  const float* gbih   = (const float*)d_in[16]; const float* gbhh   = (const float*)d_in[17];
  const float* sWih   = (const float*)d_in[18]; const float* sWhh   = (const float*)d_in[19];
  const float* sbih   = (const float*)d_in[20]; const float* sbhh   = (const float*)d_in[21];
  const float* mWih   = (const float*)d_in[22]; const float* mWhh   = (const float*)d_in[23];
  const float* mbih   = (const float*)d_in[24]; const float* mbhh   = (const float*)d_in[25];
  const float* W_lin1 = (const float*)d_in[26]; const float* b_lin1 = (const float*)d_in[27];
  const float* W_lin2 = (const float*)d_in[28]; const float* b_lin2 = (const float*)d_in[29];
  const float* W_lin3 = (const float*)d_in[30]; const float* b_lin3 = (const float*)d_in[31];
  float* dout = (float*)d_out;

  char* w = (char*)d_ws;
  float* outb = (float*)w;  w += (size_t)cN * 64 * 4;
  float* aggr = (float*)w;  w += (size_t)cN * 64 * 4;
  short* h1   = (short*)w;  w += (size_t)cE * 128 * 2;
  short* w2f  = (short*)w;  w += (size_t)64 * 8192 * 2;
  short* b2f  = (short*)w;  w += 4096 * 2;
  short* wpk  = (short*)w;  w += 28672 * 2;
  float* cntb = (float*)w;  w += cN * 4;
  float* sbuf = (float*)w;  w += cN * 4;
  float* scal = (float*)w;  w += 1088 * 4;
  int* deg  = (int*)w;  w += cN * 4;
  int* cur  = (int*)w;  w += cN * 4;
  int* rowp = (int*)w;  w += (cN + 1) * 4 + 60;   // keep alignment
  int* esrc = (int*)w;  w += cE * 4;
  int* eidx = (int*)w;  w += cE * 4;

  hipMemsetAsync(deg, 0, cN * 4, stream);
  hipMemsetAsync(cur, 0, cN * 4, stream);
  hipMemsetAsync(scal, 0, 1088 * 4, stream);

  k_lin0<<<cN * 64 / 256, 256, 0, stream>>>(x, W_lin0, b_lin0, outb);
  k_h1<<<cE * 128 / 256, 256, 0, stream>>>(edge_attr, W_e1, b_e1, h1);
  k_w2f<<<64 * 8192 / 256, 256, 0, stream>>>(W_e2, w2f);
  k_b2f<<<16, 256, 0, stream>>>(b_e2, b2f);
  k_wpack<<<112, 256, 0, stream>>>(convW, gWih, gWhh, wpk);
  k_deg<<<cE / 256, 256, 0, stream>>>(ei, deg);
  k_scan<<<1, 1024, 0, stream>>>(deg, rowp, cntb);
  k_scatter<<<cE / 256, 256, 0, stream>>>(ei, rowp, cur, esrc, eidx);

  for (int it = 0; it < 3; it++){
    k_sagg<<<cN / 16, 256, 0, stream>>>(outb, h1, w2f, b2f, rowp, esrc, eidx, aggr);
    k_nodeM<<<cN / 64, 256, 0, stream>>>(outb, aggr, cntb, wpk, convB, gbih, gbhh);
  }

  for (int st = 0; st < 3; st++){
    k_dotsF<<<cN / 64, 256, 0, stream>>>(outb, sWih, sWhh, sbih, sbhh, scal, sbuf, st);
    k_smF<<<cN / 64, 256, 0, stream>>>(outb, sbuf, scal, st);
  }

  k_memlstm<<<1, 256, 0, stream>>>(mWih, mWhh, mbih, mbhh, hx, cx, W_lin3, b_lin3, scal, dout);
  k_head<<<cT / 4, 256, 0, stream>>>(outb, nonring, scal, W_lin1, b_lin1, W_lin2, b_lin2, dout);
}